// Round 7
// baseline (425.135 us; speedup 1.0000x reference)
//
#include <hip/hip_runtime.h>
#include <math.h>

#define NB 4096            // batch
#define DIMX 784           // feature dim for x / y pdists

typedef __attribute__((ext_vector_type(8))) short bf16x8;
typedef __attribute__((ext_vector_type(4))) float f32x4;

__device__ __forceinline__ float lrelu_f(float v) { return v >= 0.f ? v : 0.01f * v; }

// round-to-nearest-even fp32 -> bf16 hi, residual -> bf16 lo
__device__ __forceinline__ void split1(float x, short& hi_s, short& lo_s) {
    unsigned u = __float_as_uint(x);
    unsigned hib = (u + 0x7FFFu + ((u >> 16) & 1u)) & 0xFFFF0000u;
    float hif = __uint_as_float(hib);
    float lo = x - hif;
    unsigned ul = __float_as_uint(lo);
    unsigned lob = (ul + 0x7FFFu + ((ul >> 16) & 1u)) >> 16;
    hi_s = (short)(hib >> 16);
    lo_s = (short)lob;
}

#define GLL(srcp, dstp) __builtin_amdgcn_global_load_lds( \
    (const __attribute__((address_space(1))) void*)(srcp), \
    (__attribute__((address_space(3))) void*)(dstp), 16, 0, 0)

// ---------------------------------------------------------------------------
// fp32 [NB][K] -> split [NB][2*KP] (hi|lo), zero pad K..KP  (x only)
// ---------------------------------------------------------------------------
__global__ __launch_bounds__(256) void split_act_kernel(
    const float* __restrict__ X, short* __restrict__ Xs, int K, int KP)
{
    const int idx = blockIdx.x * 256 + threadIdx.x;
    if (idx >= NB * KP) return;
    const int r = idx / KP, k = idx - r * KP;
    short hi = 0, lo = 0;
    if (k < K) split1(X[(size_t)r * K + k], hi, lo);
    Xs[(size_t)r * 2 * KP + k]      = hi;
    Xs[(size_t)r * 2 * KP + KP + k] = lo;
}

// fp32 W [N][K] -> split [NP][2*KP], zero pad rows/cols
__global__ __launch_bounds__(256) void split_w_kernel(
    const float* __restrict__ W, short* __restrict__ Ws, int N, int K, int NP, int KP)
{
    const int idx = blockIdx.x * 256 + threadIdx.x;
    if (idx >= NP * KP) return;
    const int r = idx / KP, k = idx - r * KP;
    short hi = 0, lo = 0;
    if (r < N && k < K) split1(W[(size_t)r * K + k], hi, lo);
    Ws[(size_t)r * 2 * KP + k]      = hi;
    Ws[(size_t)r * 2 * KP + KP + k] = lo;
}

// ---------------------------------------------------------------------------
// Row squared-norms (fp32 exact)
// ---------------------------------------------------------------------------
__global__ __launch_bounds__(256) void rowsq_kernel(
    const float* __restrict__ X, float* __restrict__ sq, int K)
{
    const int r = blockIdx.x;
    const int tid = threadIdx.x;
    float s = 0.f;
    const float* row = X + (size_t)r * K;
    for (int k = tid; k < K; k += 256) { float v = row[k]; s = fmaf(v, v, s); }
    __shared__ float red[256];
    red[tid] = s;
    __syncthreads();
    for (int off = 128; off > 0; off >>= 1) {
        if (tid < off) red[tid] += red[tid + off];
        __syncthreads();
    }
    if (tid == 0) sq[r] = red[0];
}

// ---------------------------------------------------------------------------
// Fused encoder tail: h3 = tanh(lrelu(h2 @ W12^T + b12)) (LDS only),
//                     z  = h3 @ W2^T + b2   (written to d_out)
// 64 rows per block, 64 blocks.
// ---------------------------------------------------------------------------
__global__ __launch_bounds__(256) void fused_enc_tail(
    const float* __restrict__ h2, const float* __restrict__ W12,
    const float* __restrict__ b12, const float* __restrict__ W2,
    const float* __restrict__ b2, float* __restrict__ z)
{
    __shared__ float w12l[50 * 201];
    __shared__ float h3l[64 * 51];
    __shared__ float w2l[100];
    __shared__ float b2l[2];
    __shared__ float b12l[50];
    const int t = threadIdx.x;
    const int r0 = blockIdx.x * 64;

    for (int i = t; i < 50 * 200; i += 256) {
        int n = i / 200, k = i - n * 200;
        w12l[n * 201 + k] = W12[i];
    }
    for (int i = t; i < 100; i += 256) w2l[i] = W2[i];
    if (t < 50) b12l[t] = b12[t];
    if (t < 2)  b2l[t] = b2[t];
    __syncthreads();

    for (int i = t; i < 64 * 50; i += 256) {
        const int r = i / 50, n = i - r * 50;
        const float* hrow = h2 + (size_t)(r0 + r) * 200;
        float s = b12l[n];
        #pragma unroll 4
        for (int k = 0; k < 200; ++k) s = fmaf(hrow[k], w12l[n * 201 + k], s);
        h3l[r * 51 + n] = tanhf(lrelu_f(s));
    }
    __syncthreads();

    if (t < 128) {
        const int r = t >> 1, n = t & 1;
        float s = b2l[n];
        #pragma unroll
        for (int k = 0; k < 50; ++k) s = fmaf(h3l[r * 51 + k], w2l[n * 50 + k], s);
        z[(size_t)(r0 + r) * 2 + n] = s;
    }
}

// ---------------------------------------------------------------------------
// Fused decoder head: y1 = lrelu(z @ W3^T + b3) (LDS only),
//   y2 = lrelu(y1 @ W31^T + b31) -> split bf16 hi/lo into y2s [NB][2*224]
// 64 rows per block, 64 blocks.
// ---------------------------------------------------------------------------
__global__ __launch_bounds__(256) void fused_dec_head(
    const float* __restrict__ z, const float* __restrict__ W3,
    const float* __restrict__ b3, const float* __restrict__ W31,
    const float* __restrict__ b31, short* __restrict__ y2s)
{
    __shared__ float w31l[200 * 51];
    __shared__ float y1l[64 * 51];
    __shared__ float w3l[100];
    __shared__ float b3l[50];
    __shared__ float b31l[200];
    const int t = threadIdx.x;
    const int r0 = blockIdx.x * 64;

    for (int i = t; i < 200 * 50; i += 256) {
        int n = i / 50, k = i - n * 50;
        w31l[n * 51 + k] = W31[i];
    }
    for (int i = t; i < 100; i += 256) w3l[i] = W3[i];
    if (t < 50)  b3l[t] = b3[t];
    if (t < 200) b31l[t] = b31[t];
    __syncthreads();

    for (int i = t; i < 64 * 50; i += 256) {
        const int r = i / 50, n = i - r * 50;
        const float z0 = z[(size_t)(r0 + r) * 2];
        const float z1 = z[(size_t)(r0 + r) * 2 + 1];
        float s = fmaf(z0, w3l[n * 2], fmaf(z1, w3l[n * 2 + 1], b3l[n]));
        y1l[r * 51 + n] = lrelu_f(s);
    }
    __syncthreads();

    for (int i = t; i < 64 * 224; i += 256) {
        const int r = i / 224, n = i - r * 224;
        float v = 0.f;
        if (n < 200) {
            float s = b31l[n];
            #pragma unroll
            for (int k = 0; k < 50; ++k) s = fmaf(y1l[r * 51 + k], w31l[n * 51 + k], s);
            v = lrelu_f(s);
        }
        short hi, lo; split1(v, hi, lo);
        const size_t gm = r0 + r;
        y2s[gm * 448 + n]       = hi;
        y2s[gm * 448 + 224 + n] = lo;
    }
}

// ---------------------------------------------------------------------------
// bf16-split MFMA GEMM, 3-TERM (hh + hl + lh): out = act(A @ W^T + b)
// A:[NB][2*KPi] (hi|lo), W:[NP][2*KPi]. 128x128 tile, BK=32, 4 waves,
// 2-phase pipelined. Epilogue: optional f32 C, optional split Cs [M][2*KPo].
// ---------------------------------------------------------------------------
template<int ACT, bool WF32, bool WSPLIT>
__global__ __launch_bounds__(256) void gemm3_mfma(
    const short* __restrict__ As_g, const short* __restrict__ Ws_g,
    const float* __restrict__ bias, float* __restrict__ C,
    short* __restrict__ Cs, int N, int KPi, int nchunk, int KPo)
{
    __shared__ short L[2][4][4096];   // [buf][Ah,Al,Bh,Bl][128*32]
    const int tid = threadIdx.x;
    const int w = tid >> 6, lane = tid & 63;
    const int wr = w >> 1, wc = w & 1;
    const int m0 = blockIdx.y * 128, n0 = blockIdx.x * 128;
    const int frow = lane & 15, fk = (lane >> 4) * 8;
    const int srow = tid >> 2, scol = (tid & 3) * 8;
    const int RS = 2 * KPi;
    const int ld0 = w * 512;

    const short* gA0 = As_g + (size_t)(m0 + srow) * RS + scol;
    const short* gA1 = gA0 + (size_t)64 * RS;
    const short* gB0 = Ws_g + (size_t)(n0 + srow) * RS + scol;
    const short* gB1 = gB0 + (size_t)64 * RS;

    f32x4 acc[4][4] = {};

    auto stage = [&](int buf, int km) {
        GLL(gA0 + km,       &L[buf][0][ld0]);     GLL(gA1 + km,       &L[buf][0][ld0 + 2048]);
        GLL(gA0 + KPi + km, &L[buf][1][ld0]);     GLL(gA1 + KPi + km, &L[buf][1][ld0 + 2048]);
        GLL(gB0 + km,       &L[buf][2][ld0]);     GLL(gB1 + km,       &L[buf][2][ld0 + 2048]);
        GLL(gB0 + KPi + km, &L[buf][3][ld0]);     GLL(gB1 + KPi + km, &L[buf][3][ld0 + 2048]);
    };

    stage(0, 0);
    __syncthreads();
    int buf = 0;
    #pragma unroll 1
    for (int cc = 0; cc < nchunk; ++cc) {
        if (cc + 1 < nchunk) stage(buf ^ 1, (cc + 1) * 32);

        bf16x8 ah[4], al[4], bh[4], bl[4];
        #pragma unroll
        for (int m = 0; m < 4; ++m) {
            const int ro = (wr * 64 + m * 16 + frow) * 32 + fk;
            ah[m] = *(const bf16x8*)&L[buf][0][ro];
            al[m] = *(const bf16x8*)&L[buf][1][ro];
        }
        #pragma unroll
        for (int n = 0; n < 4; ++n) {
            const int ro = (wc * 64 + n * 16 + frow) * 32 + fk;
            bh[n] = *(const bf16x8*)&L[buf][2][ro];
            bl[n] = *(const bf16x8*)&L[buf][3][ro];
        }
        #pragma unroll
        for (int m = 0; m < 4; ++m)
            #pragma unroll
            for (int n = 0; n < 4; ++n) {
                acc[m][n] = __builtin_amdgcn_mfma_f32_16x16x32_bf16(ah[m], bh[n], acc[m][n], 0, 0, 0);
                acc[m][n] = __builtin_amdgcn_mfma_f32_16x16x32_bf16(ah[m], bl[n], acc[m][n], 0, 0, 0);
                acc[m][n] = __builtin_amdgcn_mfma_f32_16x16x32_bf16(al[m], bh[n], acc[m][n], 0, 0, 0);
            }
        __syncthreads();
        buf ^= 1;
    }

    const int col0 = lane & 15;
    const int row4 = (lane >> 4) * 4;
    #pragma unroll
    for (int m = 0; m < 4; ++m) {
        #pragma unroll
        for (int r = 0; r < 4; ++r) {
            const int gm = m0 + wr * 64 + m * 16 + row4 + r;
            #pragma unroll
            for (int n = 0; n < 4; ++n) {
                const int gn = n0 + wc * 64 + n * 16 + col0;
                float v = 0.f;
                if (gn < N) {
                    v = acc[m][n][r] + bias[gn];
                    if (ACT == 1)      v = lrelu_f(v);
                    else if (ACT == 2) v = 1.f / (1.f + expf(-v));
                }
                if (WF32 && gn < N) C[(size_t)gm * N + gn] = v;
                if (WSPLIT && gn < KPo) {
                    short hi, lo; split1(v, hi, lo);
                    Cs[(size_t)gm * 2 * KPo + gn]       = hi;
                    Cs[(size_t)gm * 2 * KPo + KPo + gn] = lo;
                }
            }
        }
    }
}

// ---------------------------------------------------------------------------
// Merged asymmetric MFMA pdist:
//   blocks 0..135   : y-side, 3-term (hh+hl+lh) — heavy, launched first
//   blocks 136..271 : x-side, hh only (cross terms negligible for x — r2/r5
//                     evidence: in_diff passes with cross terms dropped)
// 256x256 tile, KP=800, BK=32, 512 thr (8 waves 2x4, wave tile 128x64),
// Ah/Al/Bh/Bl double-buffered (128 KiB LDS), 2-phase pipeline.
// Per-set bijective XCD swizzle (136 = 8*17) for L2 locality.
// ---------------------------------------------------------------------------
__global__ __launch_bounds__(512, 2) void pdist_dual(
    const short* __restrict__ xs, const short* __restrict__ ys,
    const float* __restrict__ sqx, const float* __restrict__ sqy,
    float* __restrict__ in_diff, float* __restrict__ out_diff)
{
    const int orig = blockIdx.x;
    const bool heavy = (orig < 136);
    const int o = heavy ? orig : orig - 136;
    const int b = (o & 7) * 17 + (o >> 3);     // bijective: 136 = 8*17

    const short* Xs; const float* sq; float* out;
    if (heavy) { Xs = ys; sq = sqy; out = out_diff; }
    else       { Xs = xs; sq = sqx; out = in_diff; }
    int rem = b, ti = 0;
    while (rem >= 16 - ti) { rem -= 16 - ti; ++ti; }
    const int tj = ti + rem;

    __shared__ short L[2][4][8192];   // [buf][Ah,Al,Bh,Bl][256*32] = 128 KiB
    const int tid = threadIdx.x;
    const int w = tid >> 6, lane = tid & 63;
    const int wr = w >> 2, wc = w & 3;        // 2x4 waves, wave tile 128x64
    const int i0 = ti * 256, j0 = tj * 256;
    const int frow = lane & 15, fk = (lane >> 4) * 8;
    const int srow = w * 16 + (lane >> 2), scol = (lane & 3) * 8;
    const int ld0 = w * 512;

    const short* gA = Xs + (size_t)(i0 + srow) * 1600 + scol;
    const short* gB = Xs + (size_t)(j0 + srow) * 1600 + scol;
    const size_t half = (size_t)128 * 1600;

    f32x4 acc[8][4] = {};

    auto stage = [&](int buf, int km) {
        GLL(gA + km,        &L[buf][0][ld0]);   GLL(gA + half + km,       &L[buf][0][4096 + ld0]);
        GLL(gB + km,        &L[buf][2][ld0]);   GLL(gB + half + km,       &L[buf][2][4096 + ld0]);
        if (heavy) {
            GLL(gA + 800 + km, &L[buf][1][ld0]);   GLL(gA + half + 800 + km, &L[buf][1][4096 + ld0]);
            GLL(gB + 800 + km, &L[buf][3][ld0]);   GLL(gB + half + 800 + km, &L[buf][3][4096 + ld0]);
        }
    };

    stage(0, 0);
    __syncthreads();
    int buf = 0;
    #pragma unroll 1
    for (int cc = 0; cc < 25; ++cc) {
        if (cc + 1 < 25) stage(buf ^ 1, (cc + 1) * 32);

        bf16x8 ah[8], bh[4];
        #pragma unroll
        for (int m = 0; m < 8; ++m)
            ah[m] = *(const bf16x8*)&L[buf][0][(wr * 128 + m * 16 + frow) * 32 + fk];
        #pragma unroll
        for (int n = 0; n < 4; ++n)
            bh[n] = *(const bf16x8*)&L[buf][2][(wc * 64 + n * 16 + frow) * 32 + fk];
        #pragma unroll
        for (int m = 0; m < 8; ++m)
            #pragma unroll
            for (int n = 0; n < 4; ++n)
                acc[m][n] = __builtin_amdgcn_mfma_f32_16x16x32_bf16(ah[m], bh[n], acc[m][n], 0, 0, 0);

        if (heavy) {
            {   // term 2: ah x bl
                bf16x8 bl[4];
                #pragma unroll
                for (int n = 0; n < 4; ++n)
                    bl[n] = *(const bf16x8*)&L[buf][3][(wc * 64 + n * 16 + frow) * 32 + fk];
                #pragma unroll
                for (int m = 0; m < 8; ++m)
                    #pragma unroll
                    for (int n = 0; n < 4; ++n)
                        acc[m][n] = __builtin_amdgcn_mfma_f32_16x16x32_bf16(ah[m], bl[n], acc[m][n], 0, 0, 0);
            }
            {   // term 3: al x bh
                bf16x8 al[8];
                #pragma unroll
                for (int m = 0; m < 8; ++m)
                    al[m] = *(const bf16x8*)&L[buf][1][(wr * 128 + m * 16 + frow) * 32 + fk];
                #pragma unroll
                for (int m = 0; m < 8; ++m)
                    #pragma unroll
                    for (int n = 0; n < 4; ++n)
                        acc[m][n] = __builtin_amdgcn_mfma_f32_16x16x32_bf16(al[m], bh[n], acc[m][n], 0, 0, 0);
            }
        }
        __syncthreads();
        buf ^= 1;
    }

    // epilogue: C/D layout col = lane&15, row = (lane>>4)*4 + reg
    const int col0 = lane & 15;
    const int row4 = (lane >> 4) * 4;
    float sqj_v[4];
    #pragma unroll
    for (int n = 0; n < 4; ++n)
        sqj_v[n] = sq[j0 + wc * 64 + n * 16 + col0];

    #pragma unroll
    for (int m = 0; m < 8; ++m) {
        #pragma unroll
        for (int r = 0; r < 4; ++r) {
            const int gi = i0 + wr * 128 + m * 16 + row4 + r;
            const float sqi = sq[gi];
            const int rowbase = (gi * (2 * NB - 1 - gi)) / 2 - gi - 1;
            #pragma unroll
            for (int n = 0; n < 4; ++n) {
                const int gj = j0 + wc * 64 + n * 16 + col0;
                if (gj > gi) {
                    float d2 = sqi + sqj_v[n] - 2.f * acc[m][n][r];
                    out[rowbase + gj] = sqrtf(fmaxf(d2, 0.f));
                }
            }
        }
    }
}

// ---------------------------------------------------------------------------
// pdist for 2-D latent z, triangular grid (64x64 pair-tiles, 2080 blocks)
// ---------------------------------------------------------------------------
__global__ __launch_bounds__(256) void pdist_z(
    const float* __restrict__ Z, float* __restrict__ out)
{
    int rem = blockIdx.x, ti = 0;
    while (rem >= 64 - ti) { rem -= 64 - ti; ++ti; }
    const int tj = ti + rem;

    __shared__ float zi[64][2];
    __shared__ float zj[64][2];
    const int tid = threadIdx.x;
    if (tid < 128) {
        int r = tid >> 1, c = tid & 1;
        zi[r][c] = Z[(size_t)(ti * 64 + r) * 2 + c];
        zj[r][c] = Z[(size_t)(tj * 64 + r) * 2 + c];
    }
    __syncthreads();
    const int tx = tid & 15, ty = tid >> 4;
    #pragma unroll
    for (int i = 0; i < 4; ++i) {
        const int li = ty * 4 + i;
        const int gi = ti * 64 + li;
        #pragma unroll
        for (int j = 0; j < 4; ++j) {
            const int lj = tx * 4 + j;
            const int gj = tj * 64 + lj;
            if (gj > gi) {
                float d0 = zi[li][0] - zj[lj][0];
                float d1 = zi[li][1] - zj[lj][1];
                int idx = (gi * (2 * NB - 1 - gi)) / 2 + (gj - gi - 1);
                out[idx] = sqrtf(fmaf(d0, d0, d1 * d1));
            }
        }
    }
}

// ---------------------------------------------------------------------------
extern "C" void kernel_launch(void* const* d_in, const int* in_sizes, int n_in,
                              void* d_out, int out_size, void* d_ws, size_t ws_size,
                              hipStream_t stream)
{
    const float* x       = (const float*)d_in[0];
    const float* fc1_w   = (const float*)d_in[1];
    const float* fc1_b   = (const float*)d_in[2];
    const float* fc11_w  = (const float*)d_in[3];
    const float* fc11_b  = (const float*)d_in[4];
    const float* fc12_w  = (const float*)d_in[5];
    const float* fc12_b  = (const float*)d_in[6];
    const float* fc2_w   = (const float*)d_in[7];
    const float* fc2_b   = (const float*)d_in[8];
    const float* fc3_w   = (const float*)d_in[9];
    const float* fc3_b   = (const float*)d_in[10];
    const float* fc31_w  = (const float*)d_in[11];
    const float* fc31_b  = (const float*)d_in[12];
    const float* fc32_w  = (const float*)d_in[13];
    const float* fc32_b  = (const float*)d_in[14];
    const float* fc4_w   = (const float*)d_in[15];
    const float* fc4_b   = (const float*)d_in[16];

    float* out = (float*)d_out;
    float* y        = out;                 // 4096*784
    float* in_diff  = out + 3211264;       // 8386560
    float* lat_diff = out + 11597824;      // 8386560
    float* out_diff = out + 19984384;      // 8386560
    float* z        = out + 28370944;      // 4096*2

    // ---- workspace layout (same proven footprint as round 6) ----
    float* ws   = (float*)d_ws;
    float* h2   = ws;                          // 4096*200 f32
    float* h3u  = h2  + (size_t)4096 * 200;    // (unused now)
    float* y1u  = h3u + (size_t)4096 * 50;     // (unused now)
    float* sqx  = y1u + (size_t)4096 * 50;     // 4096
    float* sqy  = sqx + 4096;                  // 4096
    short* xs   = (short*)(sqy + 4096);        // 4096*1600 (13.1 MB)
    short* ys   = xs  + (size_t)NB * 1600;     // 4096*1600 (13.1 MB)
    short* w1s  = ys  + (size_t)NB * 1600;     // 512*1600
    short* w11s = w1s  + (size_t)512 * 1600;   // 256*832
    short* w32s = w11s + (size_t)256 * 832;    // 512*448
    short* w4s  = w32s + (size_t)512 * 448;    // 896*832
    short* h1s  = w4s  + (size_t)896 * 832;    // 4096*832 (6.8 MB)
    short* y3s  = h1s;                         // alias: h1s dead after fc11
    short* y2s  = h1s  + (size_t)4096 * 832;   // 4096*448 (3.7 MB)

    const dim3 blk(256);
    auto spl = [](int tot) { return dim3((tot + 255) / 256); };

    // ---- weight splits (independent) ----
    split_w_kernel<<<spl(512 * 800), blk, 0, stream>>>(fc1_w,  w1s,  400, 784, 512, 800);
    split_w_kernel<<<spl(256 * 416), blk, 0, stream>>>(fc11_w, w11s, 200, 400, 256, 416);
    split_w_kernel<<<spl(512 * 224), blk, 0, stream>>>(fc32_w, w32s, 400, 200, 512, 224);
    split_w_kernel<<<spl(896 * 416), blk, 0, stream>>>(fc4_w,  w4s,  784, 400, 896, 416);

    // ---- x prep ----
    split_act_kernel<<<spl(NB * 800), blk, 0, stream>>>(x, xs, 784, 800);
    rowsq_kernel<<<dim3(NB), blk, 0, stream>>>(x, sqx, DIMX);

    // ---- encoder ----
    gemm3_mfma<1, false, true><<<dim3(4, 32), blk, 0, stream>>>(
        xs, w1s, fc1_b, nullptr, h1s, 400, 800, 25, 416);
    gemm3_mfma<1, true, false><<<dim3(2, 32), blk, 0, stream>>>(
        h1s, w11s, fc11_b, h2, nullptr, 200, 416, 13, 0);
    fused_enc_tail<<<dim3(64), blk, 0, stream>>>(h2, fc12_w, fc12_b, fc2_w, fc2_b, z);

    // ---- decoder ----
    fused_dec_head<<<dim3(64), blk, 0, stream>>>(z, fc3_w, fc3_b, fc31_w, fc31_b, y2s);
    gemm3_mfma<1, false, true><<<dim3(4, 32), blk, 0, stream>>>(
        y2s, w32s, fc32_b, nullptr, y3s, 400, 224, 7, 416);
    gemm3_mfma<2, true, true><<<dim3(7, 32), blk, 0, stream>>>(
        y3s, w4s, fc4_b, y, ys, 784, 416, 13, 800);

    // ---- y norms, merged asymmetric pdists ----
    rowsq_kernel<<<dim3(NB), blk, 0, stream>>>(y, sqy, DIMX);
    pdist_dual<<<dim3(272), dim3(512), 0, stream>>>(xs, ys, sqx, sqy, in_diff, out_diff);

    // ---- latent pdist ----
    pdist_z<<<dim3(2080), blk, 0, stream>>>(z, lat_diff);
}

// Round 8
// 324.164 us; speedup vs baseline: 1.3115x; 1.3115x over previous
//
#include <hip/hip_runtime.h>
#include <math.h>

#define NB 4096            // batch
#define DIMX 784           // feature dim for x / y pdists

typedef __attribute__((ext_vector_type(8))) short bf16x8;
typedef __attribute__((ext_vector_type(4))) float f32x4;

__device__ __forceinline__ float lrelu_f(float v) { return v >= 0.f ? v : 0.01f * v; }

// round-to-nearest-even fp32 -> bf16 hi, residual -> bf16 lo
__device__ __forceinline__ void split1(float x, short& hi_s, short& lo_s) {
    unsigned u = __float_as_uint(x);
    unsigned hib = (u + 0x7FFFu + ((u >> 16) & 1u)) & 0xFFFF0000u;
    float hif = __uint_as_float(hib);
    float lo = x - hif;
    unsigned ul = __float_as_uint(lo);
    unsigned lob = (ul + 0x7FFFu + ((ul >> 16) & 1u)) >> 16;
    hi_s = (short)(hib >> 16);
    lo_s = (short)lob;
}

#define GLL(srcp, dstp) __builtin_amdgcn_global_load_lds( \
    (const __attribute__((address_space(1))) void*)(srcp), \
    (__attribute__((address_space(3))) void*)(dstp), 16, 0, 0)

// ---------------------------------------------------------------------------
// fp32 [NB][K] -> split [NB][2*KP] (hi|lo), zero pad K..KP  (x only)
// ---------------------------------------------------------------------------
__global__ __launch_bounds__(256) void split_act_kernel(
    const float* __restrict__ X, short* __restrict__ Xs, int K, int KP)
{
    const int idx = blockIdx.x * 256 + threadIdx.x;
    if (idx >= NB * KP) return;
    const int r = idx / KP, k = idx - r * KP;
    short hi = 0, lo = 0;
    if (k < K) split1(X[(size_t)r * K + k], hi, lo);
    Xs[(size_t)r * 2 * KP + k]      = hi;
    Xs[(size_t)r * 2 * KP + KP + k] = lo;
}

// fp32 W [N][K] -> split [NP][2*KP], zero pad rows/cols
__global__ __launch_bounds__(256) void split_w_kernel(
    const float* __restrict__ W, short* __restrict__ Ws, int N, int K, int NP, int KP)
{
    const int idx = blockIdx.x * 256 + threadIdx.x;
    if (idx >= NP * KP) return;
    const int r = idx / KP, k = idx - r * KP;
    short hi = 0, lo = 0;
    if (r < N && k < K) split1(W[(size_t)r * K + k], hi, lo);
    Ws[(size_t)r * 2 * KP + k]      = hi;
    Ws[(size_t)r * 2 * KP + KP + k] = lo;
}

// ---------------------------------------------------------------------------
// Row squared-norms (fp32 exact)
// ---------------------------------------------------------------------------
__global__ __launch_bounds__(256) void rowsq_kernel(
    const float* __restrict__ X, float* __restrict__ sq, int K)
{
    const int r = blockIdx.x;
    const int tid = threadIdx.x;
    float s = 0.f;
    const float* row = X + (size_t)r * K;
    for (int k = tid; k < K; k += 256) { float v = row[k]; s = fmaf(v, v, s); }
    __shared__ float red[256];
    red[tid] = s;
    __syncthreads();
    for (int off = 128; off > 0; off >>= 1) {
        if (tid < off) red[tid] += red[tid + off];
        __syncthreads();
    }
    if (tid == 0) sq[r] = red[0];
}

// ---------------------------------------------------------------------------
// Small fp32 GEMM: C = act(A @ W^T + b). SPLIT: write bf16 hi/lo [M][2*KPo]
// instead of f32 (zero beyond N). ACT: 0 none, 1 lrelu, 2 sigmoid, 3 tanh(lrelu)
// ---------------------------------------------------------------------------
template<int ACT, bool SPLIT>
__global__ __launch_bounds__(256) void gemm_small(
    const float* __restrict__ A, const float* __restrict__ W,
    const float* __restrict__ bias, float* __restrict__ C,
    short* __restrict__ Cs, int M, int N, int K, int KPo)
{
    __shared__ float As[16][64];
    __shared__ float Bs[16][64];
    const int tid = threadIdx.x;
    const int tx = tid & 15, ty = tid >> 4;
    const int m0 = blockIdx.y * 64, n0 = blockIdx.x * 64;
    const int q = tid & 3, lr = tid >> 2;

    float acc[4][4] = {};

    for (int kt = 0; kt < K; kt += 16) {
        const int gk = kt + 4 * q;
        {
            const int gm = m0 + lr;
            float4 v = {0.f, 0.f, 0.f, 0.f};
            if (gm < M) {
                if (((K & 3) == 0) && (gk + 3 < K)) {
                    v = *(const float4*)(A + (size_t)gm * K + gk);
                } else {
                    const float* p = A + (size_t)gm * K;
                    if (gk     < K) v.x = p[gk];
                    if (gk + 1 < K) v.y = p[gk + 1];
                    if (gk + 2 < K) v.z = p[gk + 2];
                    if (gk + 3 < K) v.w = p[gk + 3];
                }
            }
            As[4*q+0][lr] = v.x; As[4*q+1][lr] = v.y;
            As[4*q+2][lr] = v.z; As[4*q+3][lr] = v.w;
        }
        {
            const int gn = n0 + lr;
            float4 v = {0.f, 0.f, 0.f, 0.f};
            if (gn < N) {
                if (((K & 3) == 0) && (gk + 3 < K)) {
                    v = *(const float4*)(W + (size_t)gn * K + gk);
                } else {
                    const float* p = W + (size_t)gn * K;
                    if (gk     < K) v.x = p[gk];
                    if (gk + 1 < K) v.y = p[gk + 1];
                    if (gk + 2 < K) v.z = p[gk + 2];
                    if (gk + 3 < K) v.w = p[gk + 3];
                }
            }
            Bs[4*q+0][lr] = v.x; Bs[4*q+1][lr] = v.y;
            Bs[4*q+2][lr] = v.z; Bs[4*q+3][lr] = v.w;
        }
        __syncthreads();
        #pragma unroll
        for (int kk = 0; kk < 16; ++kk) {
            float4 a = *(const float4*)&As[kk][ty * 4];
            float4 b = *(const float4*)&Bs[kk][tx * 4];
            float av[4] = {a.x, a.y, a.z, a.w};
            float bv[4] = {b.x, b.y, b.z, b.w};
            #pragma unroll
            for (int i = 0; i < 4; ++i)
                #pragma unroll
                for (int j = 0; j < 4; ++j)
                    acc[i][j] = fmaf(av[i], bv[j], acc[i][j]);
        }
        __syncthreads();
    }

    #pragma unroll
    for (int i = 0; i < 4; ++i) {
        const int gm = m0 + ty * 4 + i;
        if (gm >= M) continue;
        #pragma unroll
        for (int j = 0; j < 4; ++j) {
            const int gn = n0 + tx * 4 + j;
            float v = 0.f;
            if (gn < N) {
                v = acc[i][j] + bias[gn];
                if (ACT == 1)      v = lrelu_f(v);
                else if (ACT == 2) v = 1.f / (1.f + expf(-v));
                else if (ACT == 3) v = tanhf(lrelu_f(v));
            }
            if (SPLIT) {
                if (gn < KPo) {
                    short hi, lo; split1(v, hi, lo);
                    Cs[(size_t)gm * 2 * KPo + gn]       = hi;
                    Cs[(size_t)gm * 2 * KPo + KPo + gn] = lo;
                }
            } else {
                if (gn < N) C[(size_t)gm * N + gn] = v;
            }
        }
    }
}

// ---------------------------------------------------------------------------
// bf16-split MFMA GEMM, 3-TERM (hh + hl + lh): out = act(A @ W^T + b)
// A:[NB][2*KPi] (hi|lo), W:[NP][2*KPi]. 128x128 tile, BK=32, 4 waves.
// Counted-vmcnt pipeline: stage(next) -> vmcnt(8) -> barrier -> compute ->
// barrier (never drains the in-flight prefetch; T4).
// Epilogue: optional f32 C, optional split Cs [M][2*KPo].
// ---------------------------------------------------------------------------
template<int ACT, bool WF32, bool WSPLIT>
__global__ __launch_bounds__(256) void gemm3_mfma(
    const short* __restrict__ As_g, const short* __restrict__ Ws_g,
    const float* __restrict__ bias, float* __restrict__ C,
    short* __restrict__ Cs, int N, int KPi, int nchunk, int KPo)
{
    __shared__ short L[2][4][4096];   // [buf][Ah,Al,Bh,Bl][128*32]
    const int tid = threadIdx.x;
    const int w = tid >> 6, lane = tid & 63;
    const int wr = w >> 1, wc = w & 1;
    const int m0 = blockIdx.y * 128, n0 = blockIdx.x * 128;
    const int frow = lane & 15, fk = (lane >> 4) * 8;
    const int srow = tid >> 2, scol = (tid & 3) * 8;
    const int RS = 2 * KPi;
    const int ld0 = w * 512;

    const short* gA0 = As_g + (size_t)(m0 + srow) * RS + scol;
    const short* gA1 = gA0 + (size_t)64 * RS;
    const short* gB0 = Ws_g + (size_t)(n0 + srow) * RS + scol;
    const short* gB1 = gB0 + (size_t)64 * RS;

    f32x4 acc[4][4] = {};

    auto stage = [&](int buf, int km) {
        GLL(gA0 + km,       &L[buf][0][ld0]);     GLL(gA1 + km,       &L[buf][0][ld0 + 2048]);
        GLL(gA0 + KPi + km, &L[buf][1][ld0]);     GLL(gA1 + KPi + km, &L[buf][1][ld0 + 2048]);
        GLL(gB0 + km,       &L[buf][2][ld0]);     GLL(gB1 + km,       &L[buf][2][ld0 + 2048]);
        GLL(gB0 + KPi + km, &L[buf][3][ld0]);     GLL(gB1 + KPi + km, &L[buf][3][ld0 + 2048]);
    };

    stage(0, 0);
    asm volatile("s_waitcnt vmcnt(0)" ::: "memory");
    __builtin_amdgcn_s_barrier();
    int buf = 0;
    #pragma unroll 1
    for (int cc = 0; cc < nchunk; ++cc) {
        if (cc + 1 < nchunk) {
            stage(buf ^ 1, (cc + 1) * 32);
            asm volatile("s_waitcnt vmcnt(8)" ::: "memory");  // keep this iter's 8 in flight
        } else {
            asm volatile("s_waitcnt vmcnt(0)" ::: "memory");
        }
        __builtin_amdgcn_s_barrier();

        bf16x8 ah[4], al[4], bh[4], bl[4];
        #pragma unroll
        for (int m = 0; m < 4; ++m) {
            const int ro = (wr * 64 + m * 16 + frow) * 32 + fk;
            ah[m] = *(const bf16x8*)&L[buf][0][ro];
            al[m] = *(const bf16x8*)&L[buf][1][ro];
        }
        #pragma unroll
        for (int n = 0; n < 4; ++n) {
            const int ro = (wc * 64 + n * 16 + frow) * 32 + fk;
            bh[n] = *(const bf16x8*)&L[buf][2][ro];
            bl[n] = *(const bf16x8*)&L[buf][3][ro];
        }
        #pragma unroll
        for (int m = 0; m < 4; ++m)
            #pragma unroll
            for (int n = 0; n < 4; ++n) {
                acc[m][n] = __builtin_amdgcn_mfma_f32_16x16x32_bf16(ah[m], bh[n], acc[m][n], 0, 0, 0);
                acc[m][n] = __builtin_amdgcn_mfma_f32_16x16x32_bf16(ah[m], bl[n], acc[m][n], 0, 0, 0);
                acc[m][n] = __builtin_amdgcn_mfma_f32_16x16x32_bf16(al[m], bh[n], acc[m][n], 0, 0, 0);
            }
        __builtin_amdgcn_s_barrier();   // all reads of buf done -> next stage may overwrite
        buf ^= 1;
    }

    const int col0 = lane & 15;
    const int row4 = (lane >> 4) * 4;
    #pragma unroll
    for (int m = 0; m < 4; ++m) {
        #pragma unroll
        for (int r = 0; r < 4; ++r) {
            const int gm = m0 + wr * 64 + m * 16 + row4 + r;
            #pragma unroll
            for (int n = 0; n < 4; ++n) {
                const int gn = n0 + wc * 64 + n * 16 + col0;
                float v = 0.f;
                if (gn < N) {
                    v = acc[m][n][r] + bias[gn];
                    if (ACT == 1)      v = lrelu_f(v);
                    else if (ACT == 2) v = 1.f / (1.f + expf(-v));
                }
                if (WF32 && gn < N) C[(size_t)gm * N + gn] = v;
                if (WSPLIT && gn < KPo) {
                    short hi, lo; split1(v, hi, lo);
                    Cs[(size_t)gm * 2 * KPo + gn]       = hi;
                    Cs[(size_t)gm * 2 * KPo + KPo + gn] = lo;
                }
            }
        }
    }
}

// ---------------------------------------------------------------------------
// Merged asymmetric MFMA pdist (counted-vmcnt pipeline):
//   blocks 0..135   : y-side, 3-term (hh+hl+lh) — heavy, launched first
//   blocks 136..271 : x-side, hh only (r2/r5 evidence: in_diff passes w/o cross)
// 256x256 tile, KP=800, BK=32, 512 thr (8 waves 2x4, wave tile 128x64),
// 128 KiB LDS double-buffer, per-set bijective XCD swizzle (136 = 8*17).
// ---------------------------------------------------------------------------
__global__ __launch_bounds__(512, 2) void pdist_dual(
    const short* __restrict__ xs, const short* __restrict__ ys,
    const float* __restrict__ sqx, const float* __restrict__ sqy,
    float* __restrict__ in_diff, float* __restrict__ out_diff)
{
    const int orig = blockIdx.x;
    const bool heavy = (orig < 136);
    const int o = heavy ? orig : orig - 136;
    const int b = (o & 7) * 17 + (o >> 3);     // bijective: 136 = 8*17

    const short* Xs; const float* sq; float* out;
    if (heavy) { Xs = ys; sq = sqy; out = out_diff; }
    else       { Xs = xs; sq = sqx; out = in_diff; }
    int rem = b, ti = 0;
    while (rem >= 16 - ti) { rem -= 16 - ti; ++ti; }
    const int tj = ti + rem;

    __shared__ short L[2][4][8192];   // [buf][Ah,Al,Bh,Bl][256*32] = 128 KiB
    const int tid = threadIdx.x;
    const int w = tid >> 6, lane = tid & 63;
    const int wr = w >> 2, wc = w & 3;        // 2x4 waves, wave tile 128x64
    const int i0 = ti * 256, j0 = tj * 256;
    const int frow = lane & 15, fk = (lane >> 4) * 8;
    const int srow = w * 16 + (lane >> 2), scol = (lane & 3) * 8;
    const int ld0 = w * 512;

    const short* gA = Xs + (size_t)(i0 + srow) * 1600 + scol;
    const short* gB = Xs + (size_t)(j0 + srow) * 1600 + scol;
    const size_t half = (size_t)128 * 1600;

    f32x4 acc[8][4] = {};

    auto stage = [&](int buf, int km) {
        GLL(gA + km,        &L[buf][0][ld0]);   GLL(gA + half + km,       &L[buf][0][4096 + ld0]);
        GLL(gB + km,        &L[buf][2][ld0]);   GLL(gB + half + km,       &L[buf][2][4096 + ld0]);
        if (heavy) {
            GLL(gA + 800 + km, &L[buf][1][ld0]);   GLL(gA + half + 800 + km, &L[buf][1][4096 + ld0]);
            GLL(gB + 800 + km, &L[buf][3][ld0]);   GLL(gB + half + 800 + km, &L[buf][3][4096 + ld0]);
        }
    };

    stage(0, 0);
    asm volatile("s_waitcnt vmcnt(0)" ::: "memory");
    __builtin_amdgcn_s_barrier();
    int buf = 0;
    #pragma unroll 1
    for (int cc = 0; cc < 25; ++cc) {
        if (cc < 24) {
            stage(buf ^ 1, (cc + 1) * 32);
            if (heavy) { asm volatile("s_waitcnt vmcnt(8)" ::: "memory"); }
            else       { asm volatile("s_waitcnt vmcnt(4)" ::: "memory"); }
        } else {
            asm volatile("s_waitcnt vmcnt(0)" ::: "memory");
        }
        __builtin_amdgcn_s_barrier();

        bf16x8 ah[8], bh[4];
        #pragma unroll
        for (int m = 0; m < 8; ++m)
            ah[m] = *(const bf16x8*)&L[buf][0][(wr * 128 + m * 16 + frow) * 32 + fk];
        #pragma unroll
        for (int n = 0; n < 4; ++n)
            bh[n] = *(const bf16x8*)&L[buf][2][(wc * 64 + n * 16 + frow) * 32 + fk];
        #pragma unroll
        for (int m = 0; m < 8; ++m)
            #pragma unroll
            for (int n = 0; n < 4; ++n)
                acc[m][n] = __builtin_amdgcn_mfma_f32_16x16x32_bf16(ah[m], bh[n], acc[m][n], 0, 0, 0);

        if (heavy) {
            {   // term 2: ah x bl
                bf16x8 bl[4];
                #pragma unroll
                for (int n = 0; n < 4; ++n)
                    bl[n] = *(const bf16x8*)&L[buf][3][(wc * 64 + n * 16 + frow) * 32 + fk];
                #pragma unroll
                for (int m = 0; m < 8; ++m)
                    #pragma unroll
                    for (int n = 0; n < 4; ++n)
                        acc[m][n] = __builtin_amdgcn_mfma_f32_16x16x32_bf16(ah[m], bl[n], acc[m][n], 0, 0, 0);
            }
            {   // term 3: al x bh
                bf16x8 al[8];
                #pragma unroll
                for (int m = 0; m < 8; ++m)
                    al[m] = *(const bf16x8*)&L[buf][1][(wr * 128 + m * 16 + frow) * 32 + fk];
                #pragma unroll
                for (int m = 0; m < 8; ++m)
                    #pragma unroll
                    for (int n = 0; n < 4; ++n)
                        acc[m][n] = __builtin_amdgcn_mfma_f32_16x16x32_bf16(al[m], bh[n], acc[m][n], 0, 0, 0);
            }
        }
        __builtin_amdgcn_s_barrier();   // reads of buf done -> next stage may overwrite
        buf ^= 1;
    }

    // epilogue: C/D layout col = lane&15, row = (lane>>4)*4 + reg
    const int col0 = lane & 15;
    const int row4 = (lane >> 4) * 4;
    float sqj_v[4];
    #pragma unroll
    for (int n = 0; n < 4; ++n)
        sqj_v[n] = sq[j0 + wc * 64 + n * 16 + col0];

    #pragma unroll
    for (int m = 0; m < 8; ++m) {
        #pragma unroll
        for (int r = 0; r < 4; ++r) {
            const int gi = i0 + wr * 128 + m * 16 + row4 + r;
            const float sqi = sq[gi];
            const int rowbase = (gi * (2 * NB - 1 - gi)) / 2 - gi - 1;
            #pragma unroll
            for (int n = 0; n < 4; ++n) {
                const int gj = j0 + wc * 64 + n * 16 + col0;
                if (gj > gi) {
                    float d2 = sqi + sqj_v[n] - 2.f * acc[m][n][r];
                    out[rowbase + gj] = sqrtf(fmaxf(d2, 0.f));
                }
            }
        }
    }
}

// ---------------------------------------------------------------------------
// pdist for 2-D latent z, triangular grid (64x64 pair-tiles, 2080 blocks)
// ---------------------------------------------------------------------------
__global__ __launch_bounds__(256) void pdist_z(
    const float* __restrict__ Z, float* __restrict__ out)
{
    int rem = blockIdx.x, ti = 0;
    while (rem >= 64 - ti) { rem -= 64 - ti; ++ti; }
    const int tj = ti + rem;

    __shared__ float zi[64][2];
    __shared__ float zj[64][2];
    const int tid = threadIdx.x;
    if (tid < 128) {
        int r = tid >> 1, c = tid & 1;
        zi[r][c] = Z[(size_t)(ti * 64 + r) * 2 + c];
        zj[r][c] = Z[(size_t)(tj * 64 + r) * 2 + c];
    }
    __syncthreads();
    const int tx = tid & 15, ty = tid >> 4;
    #pragma unroll
    for (int i = 0; i < 4; ++i) {
        const int li = ty * 4 + i;
        const int gi = ti * 64 + li;
        #pragma unroll
        for (int j = 0; j < 4; ++j) {
            const int lj = tx * 4 + j;
            const int gj = tj * 64 + lj;
            if (gj > gi) {
                float d0 = zi[li][0] - zj[lj][0];
                float d1 = zi[li][1] - zj[lj][1];
                int idx = (gi * (2 * NB - 1 - gi)) / 2 + (gj - gi - 1);
                out[idx] = sqrtf(fmaf(d0, d0, d1 * d1));
            }
        }
    }
}

// ---------------------------------------------------------------------------
extern "C" void kernel_launch(void* const* d_in, const int* in_sizes, int n_in,
                              void* d_out, int out_size, void* d_ws, size_t ws_size,
                              hipStream_t stream)
{
    const float* x       = (const float*)d_in[0];
    const float* fc1_w   = (const float*)d_in[1];
    const float* fc1_b   = (const float*)d_in[2];
    const float* fc11_w  = (const float*)d_in[3];
    const float* fc11_b  = (const float*)d_in[4];
    const float* fc12_w  = (const float*)d_in[5];
    const float* fc12_b  = (const float*)d_in[6];
    const float* fc2_w   = (const float*)d_in[7];
    const float* fc2_b   = (const float*)d_in[8];
    const float* fc3_w   = (const float*)d_in[9];
    const float* fc3_b   = (const float*)d_in[10];
    const float* fc31_w  = (const float*)d_in[11];
    const float* fc31_b  = (const float*)d_in[12];
    const float* fc32_w  = (const float*)d_in[13];
    const float* fc32_b  = (const float*)d_in[14];
    const float* fc4_w   = (const float*)d_in[15];
    const float* fc4_b   = (const float*)d_in[16];

    float* out = (float*)d_out;
    float* y        = out;                 // 4096*784
    float* in_diff  = out + 3211264;       // 8386560
    float* lat_diff = out + 11597824;      // 8386560
    float* out_diff = out + 19984384;      // 8386560
    float* z        = out + 28370944;      // 4096*2

    // ---- workspace layout (round-6 proven) ----
    float* ws   = (float*)d_ws;
    float* h2   = ws;                          // 4096*200 f32
    float* h3   = h2  + (size_t)4096 * 200;    // 4096*50
    float* y1   = h3  + (size_t)4096 * 50;     // 4096*50
    float* sqx  = y1  + (size_t)4096 * 50;     // 4096
    float* sqy  = sqx + 4096;                  // 4096
    short* xs   = (short*)(sqy + 4096);        // 4096*1600 (13.1 MB)
    short* ys   = xs  + (size_t)NB * 1600;     // 4096*1600 (13.1 MB)
    short* w1s  = ys  + (size_t)NB * 1600;     // 512*1600
    short* w11s = w1s  + (size_t)512 * 1600;   // 256*832
    short* w32s = w11s + (size_t)256 * 832;    // 512*448
    short* w4s  = w32s + (size_t)512 * 448;    // 896*832
    short* h1s  = w4s  + (size_t)896 * 832;    // 4096*832 (6.8 MB)
    short* y3s  = h1s;                         // alias: h1s dead after fc11
    short* y2s  = h1s  + (size_t)4096 * 832;   // 4096*448 (3.7 MB)

    const dim3 blk(256);
    auto spl = [](int tot) { return dim3((tot + 255) / 256); };

    // ---- weight splits (independent) ----
    split_w_kernel<<<spl(512 * 800), blk, 0, stream>>>(fc1_w,  w1s,  400, 784, 512, 800);
    split_w_kernel<<<spl(256 * 416), blk, 0, stream>>>(fc11_w, w11s, 200, 400, 256, 416);
    split_w_kernel<<<spl(512 * 224), blk, 0, stream>>>(fc32_w, w32s, 400, 200, 512, 224);
    split_w_kernel<<<spl(896 * 416), blk, 0, stream>>>(fc4_w,  w4s,  784, 400, 896, 416);

    // ---- x prep ----
    split_act_kernel<<<spl(NB * 800), blk, 0, stream>>>(x, xs, 784, 800);
    rowsq_kernel<<<dim3(NB), blk, 0, stream>>>(x, sqx, DIMX);

    // ---- encoder ----
    gemm3_mfma<1, false, true><<<dim3(4, 32), blk, 0, stream>>>(
        xs, w1s, fc1_b, nullptr, h1s, 400, 800, 25, 416);
    gemm3_mfma<1, true, false><<<dim3(2, 32), blk, 0, stream>>>(
        h1s, w11s, fc11_b, h2, nullptr, 200, 416, 13, 0);
    gemm_small<3, false><<<dim3(1, 64), blk, 0, stream>>>(
        h2, fc12_w, fc12_b, h3, nullptr, NB, 50, 200, 0);
    gemm_small<0, false><<<dim3(1, 64), blk, 0, stream>>>(
        h3, fc2_w, fc2_b, z, nullptr, NB, 2, 50, 0);

    // ---- decoder ----
    gemm_small<1, false><<<dim3(1, 64), blk, 0, stream>>>(
        z, fc3_w, fc3_b, y1, nullptr, NB, 50, 2, 0);
    gemm_small<1, true><<<dim3(4, 64), blk, 0, stream>>>(
        y1, fc31_w, fc31_b, nullptr, y2s, NB, 200, 50, 224);
    gemm3_mfma<1, false, true><<<dim3(4, 32), blk, 0, stream>>>(
        y2s, w32s, fc32_b, nullptr, y3s, 400, 224, 7, 416);
    gemm3_mfma<2, true, true><<<dim3(7, 32), blk, 0, stream>>>(
        y3s, w4s, fc4_b, y, ys, 784, 416, 13, 800);

    // ---- y norms, merged asymmetric pdists ----
    rowsq_kernel<<<dim3(NB), blk, 0, stream>>>(y, sqy, DIMX);
    pdist_dual<<<dim3(272), dim3(512), 0, stream>>>(xs, ys, sqx, sqy, in_diff, out_diff);

    // ---- latent pdist ----
    pdist_z<<<dim3(2080), blk, 0, stream>>>(z, lat_diff);
}

// Round 9
// 306.468 us; speedup vs baseline: 1.3872x; 1.0577x over previous
//
#include <hip/hip_runtime.h>
#include <math.h>

#define NB 4096            // batch
#define DIMX 784           // feature dim for x / y pdists

typedef __attribute__((ext_vector_type(8))) short bf16x8;
typedef __attribute__((ext_vector_type(4))) float f32x4;

__device__ __forceinline__ float lrelu_f(float v) { return v >= 0.f ? v : 0.01f * v; }

// round-to-nearest-even fp32 -> bf16 hi, residual -> bf16 lo
__device__ __forceinline__ void split1(float x, short& hi_s, short& lo_s) {
    unsigned u = __float_as_uint(x);
    unsigned hib = (u + 0x7FFFu + ((u >> 16) & 1u)) & 0xFFFF0000u;
    float hif = __uint_as_float(hib);
    float lo = x - hif;
    unsigned ul = __float_as_uint(lo);
    unsigned lob = (ul + 0x7FFFu + ((ul >> 16) & 1u)) >> 16;
    hi_s = (short)(hib >> 16);
    lo_s = (short)lob;
}

#define GLL(srcp, dstp) __builtin_amdgcn_global_load_lds( \
    (const __attribute__((address_space(1))) void*)(srcp), \
    (__attribute__((address_space(3))) void*)(dstp), 16, 0, 0)

// ---------------------------------------------------------------------------
// All four weight splits in ONE dispatch (block-range switch).
//   [0,1600)    fc1_w  400x784 -> 512x2*800
//   [1600,2016) fc11_w 200x400 -> 256x2*416
//   [2016,2464) fc32_w 400x200 -> 512x2*224
//   [2464,3920) fc4_w  784x400 -> 896x2*416
// ---------------------------------------------------------------------------
__global__ __launch_bounds__(256) void split_w_all(
    const float* __restrict__ w1, const float* __restrict__ w11,
    const float* __restrict__ w32, const float* __restrict__ w4,
    short* __restrict__ o1, short* __restrict__ o11,
    short* __restrict__ o32, short* __restrict__ o4)
{
    const int bid = blockIdx.x;
    const float* W; short* O; int N, K, NP, KP, base;
    if (bid < 1600)      { W = w1;  O = o1;  N = 400; K = 784; NP = 512; KP = 800; base = 0; }
    else if (bid < 2016) { W = w11; O = o11; N = 200; K = 400; NP = 256; KP = 416; base = 1600; }
    else if (bid < 2464) { W = w32; O = o32; N = 400; K = 200; NP = 512; KP = 224; base = 2016; }
    else                 { W = w4;  O = o4;  N = 784; K = 400; NP = 896; KP = 416; base = 2464; }
    const int idx = (bid - base) * 256 + threadIdx.x;
    if (idx >= NP * KP) return;
    const int r = idx / KP, k = idx - r * KP;
    short hi = 0, lo = 0;
    if (r < N && k < K) split1(W[(size_t)r * K + k], hi, lo);
    O[(size_t)r * 2 * KP + k]      = hi;
    O[(size_t)r * 2 * KP + KP + k] = lo;
}

// ---------------------------------------------------------------------------
// Fused x prep: one block per row. Reads x row once (float4), writes split
// [hi(800)|lo(800)] and fp32 row squared-norm.
// ---------------------------------------------------------------------------
__global__ __launch_bounds__(256) void split_x_rowsq(
    const float* __restrict__ X, short* __restrict__ Xs, float* __restrict__ sq)
{
    const int r = blockIdx.x, t = threadIdx.x;
    float s = 0.f;
    if (t < 200) {
        const int k0 = t * 4;
        short h[4] = {0, 0, 0, 0}, l[4] = {0, 0, 0, 0};
        if (k0 < 784) {   // 784 = 196*4, so t<196 full quads
            float4 v = *(const float4*)(X + (size_t)r * 784 + k0);
            split1(v.x, h[0], l[0]); split1(v.y, h[1], l[1]);
            split1(v.z, h[2], l[2]); split1(v.w, h[3], l[3]);
            s = v.x * v.x + v.y * v.y + v.z * v.z + v.w * v.w;
        }
        *(uint2*)&Xs[(size_t)r * 1600 + k0]       = *(const uint2*)h;
        *(uint2*)&Xs[(size_t)r * 1600 + 800 + k0] = *(const uint2*)l;
    }
    __shared__ float red[256];
    red[t] = s;
    __syncthreads();
    for (int off = 128; off > 0; off >>= 1) {
        if (t < off) red[t] += red[t + off];
        __syncthreads();
    }
    if (t == 0) sq[r] = red[0];
}

// ---------------------------------------------------------------------------
// Row squared-norms (fp32 exact) — used for y
// ---------------------------------------------------------------------------
__global__ __launch_bounds__(256) void rowsq_kernel(
    const float* __restrict__ X, float* __restrict__ sq, int K)
{
    const int r = blockIdx.x;
    const int tid = threadIdx.x;
    float s = 0.f;
    const float* row = X + (size_t)r * K;
    for (int k = tid; k < K; k += 256) { float v = row[k]; s = fmaf(v, v, s); }
    __shared__ float red[256];
    red[tid] = s;
    __syncthreads();
    for (int off = 128; off > 0; off >>= 1) {
        if (tid < off) red[tid] += red[tid + off];
        __syncthreads();
    }
    if (tid == 0) sq[r] = red[0];
}

// ---------------------------------------------------------------------------
// Small fp32 GEMM: C = act(A @ W^T + b). SPLIT: write bf16 hi/lo [M][2*KPo].
// ACT: 0 none, 1 lrelu, 2 sigmoid, 3 tanh(lrelu)
// ---------------------------------------------------------------------------
template<int ACT, bool SPLIT>
__global__ __launch_bounds__(256) void gemm_small(
    const float* __restrict__ A, const float* __restrict__ W,
    const float* __restrict__ bias, float* __restrict__ C,
    short* __restrict__ Cs, int M, int N, int K, int KPo)
{
    __shared__ float As[16][64];
    __shared__ float Bs[16][64];
    const int tid = threadIdx.x;
    const int tx = tid & 15, ty = tid >> 4;
    const int m0 = blockIdx.y * 64, n0 = blockIdx.x * 64;
    const int q = tid & 3, lr = tid >> 2;

    float acc[4][4] = {};

    for (int kt = 0; kt < K; kt += 16) {
        const int gk = kt + 4 * q;
        {
            const int gm = m0 + lr;
            float4 v = {0.f, 0.f, 0.f, 0.f};
            if (gm < M) {
                if (((K & 3) == 0) && (gk + 3 < K)) {
                    v = *(const float4*)(A + (size_t)gm * K + gk);
                } else {
                    const float* p = A + (size_t)gm * K;
                    if (gk     < K) v.x = p[gk];
                    if (gk + 1 < K) v.y = p[gk + 1];
                    if (gk + 2 < K) v.z = p[gk + 2];
                    if (gk + 3 < K) v.w = p[gk + 3];
                }
            }
            As[4*q+0][lr] = v.x; As[4*q+1][lr] = v.y;
            As[4*q+2][lr] = v.z; As[4*q+3][lr] = v.w;
        }
        {
            const int gn = n0 + lr;
            float4 v = {0.f, 0.f, 0.f, 0.f};
            if (gn < N) {
                if (((K & 3) == 0) && (gk + 3 < K)) {
                    v = *(const float4*)(W + (size_t)gn * K + gk);
                } else {
                    const float* p = W + (size_t)gn * K;
                    if (gk     < K) v.x = p[gk];
                    if (gk + 1 < K) v.y = p[gk + 1];
                    if (gk + 2 < K) v.z = p[gk + 2];
                    if (gk + 3 < K) v.w = p[gk + 3];
                }
            }
            Bs[4*q+0][lr] = v.x; Bs[4*q+1][lr] = v.y;
            Bs[4*q+2][lr] = v.z; Bs[4*q+3][lr] = v.w;
        }
        __syncthreads();
        #pragma unroll
        for (int kk = 0; kk < 16; ++kk) {
            float4 a = *(const float4*)&As[kk][ty * 4];
            float4 b = *(const float4*)&Bs[kk][tx * 4];
            float av[4] = {a.x, a.y, a.z, a.w};
            float bv[4] = {b.x, b.y, b.z, b.w};
            #pragma unroll
            for (int i = 0; i < 4; ++i)
                #pragma unroll
                for (int j = 0; j < 4; ++j)
                    acc[i][j] = fmaf(av[i], bv[j], acc[i][j]);
        }
        __syncthreads();
    }

    #pragma unroll
    for (int i = 0; i < 4; ++i) {
        const int gm = m0 + ty * 4 + i;
        if (gm >= M) continue;
        #pragma unroll
        for (int j = 0; j < 4; ++j) {
            const int gn = n0 + tx * 4 + j;
            float v = 0.f;
            if (gn < N) {
                v = acc[i][j] + bias[gn];
                if (ACT == 1)      v = lrelu_f(v);
                else if (ACT == 2) v = 1.f / (1.f + expf(-v));
                else if (ACT == 3) v = tanhf(lrelu_f(v));
            }
            if (SPLIT) {
                if (gn < KPo) {
                    short hi, lo; split1(v, hi, lo);
                    Cs[(size_t)gm * 2 * KPo + gn]       = hi;
                    Cs[(size_t)gm * 2 * KPo + KPo + gn] = lo;
                }
            } else {
                if (gn < N) C[(size_t)gm * N + gn] = v;
            }
        }
    }
}

// ---------------------------------------------------------------------------
// bf16-split MFMA GEMM, 3-TERM (hh + hl + lh): out = act(A @ W^T + b)
// 128x128 tile, BK=32, 4 waves, counted-vmcnt double-buffer pipeline.
// ---------------------------------------------------------------------------
template<int ACT, bool WF32, bool WSPLIT>
__global__ __launch_bounds__(256) void gemm3_mfma(
    const short* __restrict__ As_g, const short* __restrict__ Ws_g,
    const float* __restrict__ bias, float* __restrict__ C,
    short* __restrict__ Cs, int N, int KPi, int nchunk, int KPo)
{
    __shared__ short L[2][4][4096];   // [buf][Ah,Al,Bh,Bl][128*32]
    const int tid = threadIdx.x;
    const int w = tid >> 6, lane = tid & 63;
    const int wr = w >> 1, wc = w & 1;
    const int m0 = blockIdx.y * 128, n0 = blockIdx.x * 128;
    const int frow = lane & 15, fk = (lane >> 4) * 8;
    const int srow = tid >> 2, scol = (tid & 3) * 8;
    const int RS = 2 * KPi;
    const int ld0 = w * 512;

    const short* gA0 = As_g + (size_t)(m0 + srow) * RS + scol;
    const short* gA1 = gA0 + (size_t)64 * RS;
    const short* gB0 = Ws_g + (size_t)(n0 + srow) * RS + scol;
    const short* gB1 = gB0 + (size_t)64 * RS;

    f32x4 acc[4][4] = {};

    auto stage = [&](int buf, int km) {
        GLL(gA0 + km,       &L[buf][0][ld0]);     GLL(gA1 + km,       &L[buf][0][ld0 + 2048]);
        GLL(gA0 + KPi + km, &L[buf][1][ld0]);     GLL(gA1 + KPi + km, &L[buf][1][ld0 + 2048]);
        GLL(gB0 + km,       &L[buf][2][ld0]);     GLL(gB1 + km,       &L[buf][2][ld0 + 2048]);
        GLL(gB0 + KPi + km, &L[buf][3][ld0]);     GLL(gB1 + KPi + km, &L[buf][3][ld0 + 2048]);
    };

    stage(0, 0);
    asm volatile("s_waitcnt vmcnt(0)" ::: "memory");
    __builtin_amdgcn_s_barrier();
    int buf = 0;
    #pragma unroll 1
    for (int cc = 0; cc < nchunk; ++cc) {
        if (cc + 1 < nchunk) {
            stage(buf ^ 1, (cc + 1) * 32);
            asm volatile("s_waitcnt vmcnt(8)" ::: "memory");
        } else {
            asm volatile("s_waitcnt vmcnt(0)" ::: "memory");
        }
        __builtin_amdgcn_s_barrier();

        bf16x8 ah[4], al[4], bh[4], bl[4];
        #pragma unroll
        for (int m = 0; m < 4; ++m) {
            const int ro = (wr * 64 + m * 16 + frow) * 32 + fk;
            ah[m] = *(const bf16x8*)&L[buf][0][ro];
            al[m] = *(const bf16x8*)&L[buf][1][ro];
        }
        #pragma unroll
        for (int n = 0; n < 4; ++n) {
            const int ro = (wc * 64 + n * 16 + frow) * 32 + fk;
            bh[n] = *(const bf16x8*)&L[buf][2][ro];
            bl[n] = *(const bf16x8*)&L[buf][3][ro];
        }
        #pragma unroll
        for (int m = 0; m < 4; ++m)
            #pragma unroll
            for (int n = 0; n < 4; ++n) {
                acc[m][n] = __builtin_amdgcn_mfma_f32_16x16x32_bf16(ah[m], bh[n], acc[m][n], 0, 0, 0);
                acc[m][n] = __builtin_amdgcn_mfma_f32_16x16x32_bf16(ah[m], bl[n], acc[m][n], 0, 0, 0);
                acc[m][n] = __builtin_amdgcn_mfma_f32_16x16x32_bf16(al[m], bh[n], acc[m][n], 0, 0, 0);
            }
        __builtin_amdgcn_s_barrier();
        buf ^= 1;
    }

    const int col0 = lane & 15;
    const int row4 = (lane >> 4) * 4;
    #pragma unroll
    for (int m = 0; m < 4; ++m) {
        #pragma unroll
        for (int r = 0; r < 4; ++r) {
            const int gm = m0 + wr * 64 + m * 16 + row4 + r;
            #pragma unroll
            for (int n = 0; n < 4; ++n) {
                const int gn = n0 + wc * 64 + n * 16 + col0;
                float v = 0.f;
                if (gn < N) {
                    v = acc[m][n][r] + bias[gn];
                    if (ACT == 1)      v = lrelu_f(v);
                    else if (ACT == 2) v = 1.f / (1.f + expf(-v));
                }
                if (WF32 && gn < N) C[(size_t)gm * N + gn] = v;
                if (WSPLIT && gn < KPo) {
                    short hi, lo; split1(v, hi, lo);
                    Cs[(size_t)gm * 2 * KPo + gn]       = hi;
                    Cs[(size_t)gm * 2 * KPo + KPo + gn] = lo;
                }
            }
        }
    }
}

// ---------------------------------------------------------------------------
// Mixed-granularity merged pdist:
//   blocks 0..135   : y-side heavy, 256x256 tile, 3-term (hh+hl+lh)
//   blocks 136..663 : x-side light, 128x128 tile, hh-only (528 tri-tiles)
// 512 threads. Heavy path identical to round-8's proven kernel; light path
// backfills CUs as heavies finish -> removes the 2-round tail quantization.
// Per-set bijective XCD swizzle (136 = 8*17, 528 = 8*66).
// ---------------------------------------------------------------------------
__global__ __launch_bounds__(512, 2) void pdist_mixed(
    const short* __restrict__ xs, const short* __restrict__ ys,
    const float* __restrict__ sqx, const float* __restrict__ sqy,
    float* __restrict__ in_diff, float* __restrict__ out_diff)
{
    __shared__ short L[2][4][8192];   // heavy: [buf][Ah,Al,Bh,Bl][256*32] = 128 KiB
    const int tid = threadIdx.x;
    const int w = tid >> 6, lane = tid & 63;
    const int frow = lane & 15, fk = (lane >> 4) * 8;
    const int col0 = lane & 15;
    const int row4 = (lane >> 4) * 4;
    const int orig = blockIdx.x;

    if (orig < 136) {
        // ---------------- heavy: y-side 256x256, 3-term ----------------
        const int b = (orig & 7) * 17 + (orig >> 3);
        int rem = b, ti = 0;
        while (rem >= 16 - ti) { rem -= 16 - ti; ++ti; }
        const int tj = ti + rem;

        const int wr = w >> 2, wc = w & 3;        // 2x4 waves, wave tile 128x64
        const int i0 = ti * 256, j0 = tj * 256;
        const int srow = w * 16 + (lane >> 2), scol = (lane & 3) * 8;
        const int ld0 = w * 512;

        const short* gA = ys + (size_t)(i0 + srow) * 1600 + scol;
        const short* gB = ys + (size_t)(j0 + srow) * 1600 + scol;
        const size_t half = (size_t)128 * 1600;

        f32x4 acc[8][4] = {};

        auto stage = [&](int buf, int km) {
            GLL(gA + km,       &L[buf][0][ld0]);   GLL(gA + half + km,       &L[buf][0][4096 + ld0]);
            GLL(gB + km,       &L[buf][2][ld0]);   GLL(gB + half + km,       &L[buf][2][4096 + ld0]);
            GLL(gA + 800 + km, &L[buf][1][ld0]);   GLL(gA + half + 800 + km, &L[buf][1][4096 + ld0]);
            GLL(gB + 800 + km, &L[buf][3][ld0]);   GLL(gB + half + 800 + km, &L[buf][3][4096 + ld0]);
        };

        stage(0, 0);
        asm volatile("s_waitcnt vmcnt(0)" ::: "memory");
        __builtin_amdgcn_s_barrier();
        int buf = 0;
        #pragma unroll 1
        for (int cc = 0; cc < 25; ++cc) {
            if (cc < 24) {
                stage(buf ^ 1, (cc + 1) * 32);
                asm volatile("s_waitcnt vmcnt(8)" ::: "memory");
            } else {
                asm volatile("s_waitcnt vmcnt(0)" ::: "memory");
            }
            __builtin_amdgcn_s_barrier();

            bf16x8 ah[8], bh[4];
            #pragma unroll
            for (int m = 0; m < 8; ++m)
                ah[m] = *(const bf16x8*)&L[buf][0][(wr * 128 + m * 16 + frow) * 32 + fk];
            #pragma unroll
            for (int n = 0; n < 4; ++n)
                bh[n] = *(const bf16x8*)&L[buf][2][(wc * 64 + n * 16 + frow) * 32 + fk];
            #pragma unroll
            for (int m = 0; m < 8; ++m)
                #pragma unroll
                for (int n = 0; n < 4; ++n)
                    acc[m][n] = __builtin_amdgcn_mfma_f32_16x16x32_bf16(ah[m], bh[n], acc[m][n], 0, 0, 0);
            {   // term 2: ah x bl
                bf16x8 bl[4];
                #pragma unroll
                for (int n = 0; n < 4; ++n)
                    bl[n] = *(const bf16x8*)&L[buf][3][(wc * 64 + n * 16 + frow) * 32 + fk];
                #pragma unroll
                for (int m = 0; m < 8; ++m)
                    #pragma unroll
                    for (int n = 0; n < 4; ++n)
                        acc[m][n] = __builtin_amdgcn_mfma_f32_16x16x32_bf16(ah[m], bl[n], acc[m][n], 0, 0, 0);
            }
            {   // term 3: al x bh
                bf16x8 al[8];
                #pragma unroll
                for (int m = 0; m < 8; ++m)
                    al[m] = *(const bf16x8*)&L[buf][1][(wr * 128 + m * 16 + frow) * 32 + fk];
                #pragma unroll
                for (int m = 0; m < 8; ++m)
                    #pragma unroll
                    for (int n = 0; n < 4; ++n)
                        acc[m][n] = __builtin_amdgcn_mfma_f32_16x16x32_bf16(al[m], bh[n], acc[m][n], 0, 0, 0);
            }
            __builtin_amdgcn_s_barrier();
            buf ^= 1;
        }

        float sqj_v[4];
        #pragma unroll
        for (int n = 0; n < 4; ++n)
            sqj_v[n] = sqy[j0 + wc * 64 + n * 16 + col0];

        #pragma unroll
        for (int m = 0; m < 8; ++m) {
            #pragma unroll
            for (int r = 0; r < 4; ++r) {
                const int gi = i0 + wr * 128 + m * 16 + row4 + r;
                const float sqi = sqy[gi];
                const int rowbase = (gi * (2 * NB - 1 - gi)) / 2 - gi - 1;
                #pragma unroll
                for (int n = 0; n < 4; ++n) {
                    const int gj = j0 + wc * 64 + n * 16 + col0;
                    if (gj > gi) {
                        float d2 = sqi + sqj_v[n] - 2.f * acc[m][n][r];
                        out_diff[rowbase + gj] = sqrtf(fmaxf(d2, 0.f));
                    }
                }
            }
        }
    } else {
        // ---------------- light: x-side 128x128, hh-only ----------------
        const int o = orig - 136;
        const int b = (o & 7) * 66 + (o >> 3);    // bijective: 528 = 8*66
        int rem = b, ti = 0;
        while (rem >= 32 - ti) { rem -= 32 - ti; ++ti; }
        const int tj = ti + rem;

        const int wr = w >> 2, wc = w & 3;        // wave tile 64x32
        const int i0 = ti * 128, j0 = tj * 128;
        const int srow = tid >> 2, scol = (tid & 3) * 8;

        const short* gA = xs + (size_t)(i0 + srow) * 1600 + scol;
        const short* gB = xs + (size_t)(j0 + srow) * 1600 + scol;

        f32x4 acc[4][2] = {};

        auto stageL = [&](int buf, int km) {
            GLL(gA + km, &L[buf][0][w * 512]);
            GLL(gB + km, &L[buf][2][w * 512]);
        };

        stageL(0, 0);
        asm volatile("s_waitcnt vmcnt(0)" ::: "memory");
        __builtin_amdgcn_s_barrier();
        int buf = 0;
        #pragma unroll 1
        for (int cc = 0; cc < 25; ++cc) {
            if (cc < 24) {
                stageL(buf ^ 1, (cc + 1) * 32);
                asm volatile("s_waitcnt vmcnt(2)" ::: "memory");
            } else {
                asm volatile("s_waitcnt vmcnt(0)" ::: "memory");
            }
            __builtin_amdgcn_s_barrier();

            bf16x8 a[4], bb[2];
            #pragma unroll
            for (int m = 0; m < 4; ++m)
                a[m] = *(const bf16x8*)&L[buf][0][(wr * 64 + m * 16 + frow) * 32 + fk];
            #pragma unroll
            for (int n = 0; n < 2; ++n)
                bb[n] = *(const bf16x8*)&L[buf][2][(wc * 32 + n * 16 + frow) * 32 + fk];
            #pragma unroll
            for (int m = 0; m < 4; ++m)
                #pragma unroll
                for (int n = 0; n < 2; ++n)
                    acc[m][n] = __builtin_amdgcn_mfma_f32_16x16x32_bf16(a[m], bb[n], acc[m][n], 0, 0, 0);
            __builtin_amdgcn_s_barrier();
            buf ^= 1;
        }

        float sqj_v[2];
        #pragma unroll
        for (int n = 0; n < 2; ++n)
            sqj_v[n] = sqx[j0 + wc * 32 + n * 16 + col0];

        #pragma unroll
        for (int m = 0; m < 4; ++m) {
            #pragma unroll
            for (int r = 0; r < 4; ++r) {
                const int gi = i0 + wr * 64 + m * 16 + row4 + r;
                const float sqi = sqx[gi];
                const int rowbase = (gi * (2 * NB - 1 - gi)) / 2 - gi - 1;
                #pragma unroll
                for (int n = 0; n < 2; ++n) {
                    const int gj = j0 + wc * 32 + n * 16 + col0;
                    if (gj > gi) {
                        float d2 = sqi + sqj_v[n] - 2.f * acc[m][n][r];
                        in_diff[rowbase + gj] = sqrtf(fmaxf(d2, 0.f));
                    }
                }
            }
        }
    }
}

// ---------------------------------------------------------------------------
// pdist for 2-D latent z, triangular grid (64x64 pair-tiles, 2080 blocks)
// ---------------------------------------------------------------------------
__global__ __launch_bounds__(256) void pdist_z(
    const float* __restrict__ Z, float* __restrict__ out)
{
    int rem = blockIdx.x, ti = 0;
    while (rem >= 64 - ti) { rem -= 64 - ti; ++ti; }
    const int tj = ti + rem;

    __shared__ float zi[64][2];
    __shared__ float zj[64][2];
    const int tid = threadIdx.x;
    if (tid < 128) {
        int r = tid >> 1, c = tid & 1;
        zi[r][c] = Z[(size_t)(ti * 64 + r) * 2 + c];
        zj[r][c] = Z[(size_t)(tj * 64 + r) * 2 + c];
    }
    __syncthreads();
    const int tx = tid & 15, ty = tid >> 4;
    #pragma unroll
    for (int i = 0; i < 4; ++i) {
        const int li = ty * 4 + i;
        const int gi = ti * 64 + li;
        #pragma unroll
        for (int j = 0; j < 4; ++j) {
            const int lj = tx * 4 + j;
            const int gj = tj * 64 + lj;
            if (gj > gi) {
                float d0 = zi[li][0] - zj[lj][0];
                float d1 = zi[li][1] - zj[lj][1];
                int idx = (gi * (2 * NB - 1 - gi)) / 2 + (gj - gi - 1);
                out[idx] = sqrtf(fmaf(d0, d0, d1 * d1));
            }
        }
    }
}

// ---------------------------------------------------------------------------
extern "C" void kernel_launch(void* const* d_in, const int* in_sizes, int n_in,
                              void* d_out, int out_size, void* d_ws, size_t ws_size,
                              hipStream_t stream)
{
    const float* x       = (const float*)d_in[0];
    const float* fc1_w   = (const float*)d_in[1];
    const float* fc1_b   = (const float*)d_in[2];
    const float* fc11_w  = (const float*)d_in[3];
    const float* fc11_b  = (const float*)d_in[4];
    const float* fc12_w  = (const float*)d_in[5];
    const float* fc12_b  = (const float*)d_in[6];
    const float* fc2_w   = (const float*)d_in[7];
    const float* fc2_b   = (const float*)d_in[8];
    const float* fc3_w   = (const float*)d_in[9];
    const float* fc3_b   = (const float*)d_in[10];
    const float* fc31_w  = (const float*)d_in[11];
    const float* fc31_b  = (const float*)d_in[12];
    const float* fc32_w  = (const float*)d_in[13];
    const float* fc32_b  = (const float*)d_in[14];
    const float* fc4_w   = (const float*)d_in[15];
    const float* fc4_b   = (const float*)d_in[16];

    float* out = (float*)d_out;
    float* y        = out;                 // 4096*784
    float* in_diff  = out + 3211264;       // 8386560
    float* lat_diff = out + 11597824;      // 8386560
    float* out_diff = out + 19984384;      // 8386560
    float* z        = out + 28370944;      // 4096*2

    // ---- workspace layout (round-6/8 proven) ----
    float* ws   = (float*)d_ws;
    float* h2   = ws;                          // 4096*200 f32
    float* h3   = h2  + (size_t)4096 * 200;    // 4096*50
    float* y1   = h3  + (size_t)4096 * 50;     // 4096*50
    float* sqx  = y1  + (size_t)4096 * 50;     // 4096
    float* sqy  = sqx + 4096;                  // 4096
    short* xs   = (short*)(sqy + 4096);        // 4096*1600 (13.1 MB)
    short* ys   = xs  + (size_t)NB * 1600;     // 4096*1600 (13.1 MB)
    short* w1s  = ys  + (size_t)NB * 1600;     // 512*1600
    short* w11s = w1s  + (size_t)512 * 1600;   // 256*832
    short* w32s = w11s + (size_t)256 * 832;    // 512*448
    short* w4s  = w32s + (size_t)512 * 448;    // 896*832
    short* h1s  = w4s  + (size_t)896 * 832;    // 4096*832 (6.8 MB)
    short* y3s  = h1s;                         // alias: h1s dead after fc11
    short* y2s  = h1s  + (size_t)4096 * 832;   // 4096*448 (3.7 MB)

    const dim3 blk(256);

    // ---- all weight splits, one dispatch ----
    split_w_all<<<dim3(3920), blk, 0, stream>>>(
        fc1_w, fc11_w, fc32_w, fc4_w, w1s, w11s, w32s, w4s);

    // ---- x prep: split + rowsq fused ----
    split_x_rowsq<<<dim3(NB), blk, 0, stream>>>(x, xs, sqx);

    // ---- encoder ----
    gemm3_mfma<1, false, true><<<dim3(4, 32), blk, 0, stream>>>(
        xs, w1s, fc1_b, nullptr, h1s, 400, 800, 25, 416);
    gemm3_mfma<1, true, false><<<dim3(2, 32), blk, 0, stream>>>(
        h1s, w11s, fc11_b, h2, nullptr, 200, 416, 13, 0);
    gemm_small<3, false><<<dim3(1, 64), blk, 0, stream>>>(
        h2, fc12_w, fc12_b, h3, nullptr, NB, 50, 200, 0);
    gemm_small<0, false><<<dim3(1, 64), blk, 0, stream>>>(
        h3, fc2_w, fc2_b, z, nullptr, NB, 2, 50, 0);

    // ---- decoder ----
    gemm_small<1, false><<<dim3(1, 64), blk, 0, stream>>>(
        z, fc3_w, fc3_b, y1, nullptr, NB, 50, 2, 0);
    gemm_small<1, true><<<dim3(4, 64), blk, 0, stream>>>(
        y1, fc31_w, fc31_b, nullptr, y2s, NB, 200, 50, 224);
    gemm3_mfma<1, false, true><<<dim3(4, 32), blk, 0, stream>>>(
        y2s, w32s, fc32_b, nullptr, y3s, 400, 224, 7, 416);
    gemm3_mfma<2, true, true><<<dim3(7, 32), blk, 0, stream>>>(
        y3s, w4s, fc4_b, y, ys, 784, 416, 13, 800);

    // ---- y norms, merged mixed-granularity pdists ----
    rowsq_kernel<<<dim3(NB), blk, 0, stream>>>(y, sqy, DIMX);
    pdist_mixed<<<dim3(664), dim3(512), 0, stream>>>(xs, ys, sqx, sqy, in_diff, out_diff);

    // ---- latent pdist ----
    pdist_z<<<dim3(2080), blk, 0, stream>>>(z, lat_diff);
}

// Round 10
// 276.332 us; speedup vs baseline: 1.5385x; 1.1091x over previous
//
#include <hip/hip_runtime.h>
#include <math.h>

#define NB 4096            // batch
#define DIMX 784           // feature dim for x / y pdists

typedef __attribute__((ext_vector_type(8))) short bf16x8;
typedef __attribute__((ext_vector_type(4))) float f32x4;

__device__ __forceinline__ float lrelu_f(float v) { return v >= 0.f ? v : 0.01f * v; }

// round-to-nearest-even fp32 -> bf16 hi, residual -> bf16 lo
__device__ __forceinline__ void split1(float x, short& hi_s, short& lo_s) {
    unsigned u = __float_as_uint(x);
    unsigned hib = (u + 0x7FFFu + ((u >> 16) & 1u)) & 0xFFFF0000u;
    float hif = __uint_as_float(hib);
    float lo = x - hif;
    unsigned ul = __float_as_uint(lo);
    unsigned lob = (ul + 0x7FFFu + ((ul >> 16) & 1u)) >> 16;
    hi_s = (short)(hib >> 16);
    lo_s = (short)lob;
}

#define GLL(srcp, dstp) __builtin_amdgcn_global_load_lds( \
    (const __attribute__((address_space(1))) void*)(srcp), \
    (__attribute__((address_space(3))) void*)(dstp), 16, 0, 0)

// ---------------------------------------------------------------------------
// All four weight splits in ONE dispatch (block-range switch).
// ---------------------------------------------------------------------------
__global__ __launch_bounds__(256) void split_w_all(
    const float* __restrict__ w1, const float* __restrict__ w11,
    const float* __restrict__ w32, const float* __restrict__ w4,
    short* __restrict__ o1, short* __restrict__ o11,
    short* __restrict__ o32, short* __restrict__ o4)
{
    const int bid = blockIdx.x;
    const float* W; short* O; int N, K, NP, KP, base;
    if (bid < 1600)      { W = w1;  O = o1;  N = 400; K = 784; NP = 512; KP = 800; base = 0; }
    else if (bid < 2016) { W = w11; O = o11; N = 200; K = 400; NP = 256; KP = 416; base = 1600; }
    else if (bid < 2464) { W = w32; O = o32; N = 400; K = 200; NP = 512; KP = 224; base = 2016; }
    else                 { W = w4;  O = o4;  N = 784; K = 400; NP = 896; KP = 416; base = 2464; }
    const int idx = (bid - base) * 256 + threadIdx.x;
    if (idx >= NP * KP) return;
    const int r = idx / KP, k = idx - r * KP;
    short hi = 0, lo = 0;
    if (r < N && k < K) split1(W[(size_t)r * K + k], hi, lo);
    O[(size_t)r * 2 * KP + k]      = hi;
    O[(size_t)r * 2 * KP + KP + k] = lo;
}

// ---------------------------------------------------------------------------
// Fused x prep: one block per row. split [hi(800)|lo(800)] + row sq-norm.
// ---------------------------------------------------------------------------
__global__ __launch_bounds__(256) void split_x_rowsq(
    const float* __restrict__ X, short* __restrict__ Xs, float* __restrict__ sq)
{
    const int r = blockIdx.x, t = threadIdx.x;
    float s = 0.f;
    if (t < 200) {
        const int k0 = t * 4;
        short h[4] = {0, 0, 0, 0}, l[4] = {0, 0, 0, 0};
        if (k0 < 784) {
            float4 v = *(const float4*)(X + (size_t)r * 784 + k0);
            split1(v.x, h[0], l[0]); split1(v.y, h[1], l[1]);
            split1(v.z, h[2], l[2]); split1(v.w, h[3], l[3]);
            s = v.x * v.x + v.y * v.y + v.z * v.z + v.w * v.w;
        }
        *(uint2*)&Xs[(size_t)r * 1600 + k0]       = *(const uint2*)h;
        *(uint2*)&Xs[(size_t)r * 1600 + 800 + k0] = *(const uint2*)l;
    }
    __shared__ float red[256];
    red[t] = s;
    __syncthreads();
    for (int off = 128; off > 0; off >>= 1) {
        if (t < off) red[t] += red[t + off];
        __syncthreads();
    }
    if (t == 0) sq[r] = red[0];
}

// ---------------------------------------------------------------------------
// Row squared-norms (fp32 exact) — y
// ---------------------------------------------------------------------------
__global__ __launch_bounds__(256) void rowsq_kernel(
    const float* __restrict__ X, float* __restrict__ sq, int K)
{
    const int r = blockIdx.x;
    const int tid = threadIdx.x;
    float s = 0.f;
    const float* row = X + (size_t)r * K;
    for (int k = tid; k < K; k += 256) { float v = row[k]; s = fmaf(v, v, s); }
    __shared__ float red[256];
    red[tid] = s;
    __syncthreads();
    for (int off = 128; off > 0; off >>= 1) {
        if (tid < off) red[tid] += red[tid + off];
        __syncthreads();
    }
    if (tid == 0) sq[r] = red[0];
}

// ---------------------------------------------------------------------------
// bf16-split MFMA GEMM, 3-TERM (hh + hl + lh). 128x128 tile, BK=32, 4 waves,
// counted-vmcnt double-buffer pipeline. (r9-proven)
// ---------------------------------------------------------------------------
template<int ACT, bool WF32, bool WSPLIT>
__global__ __launch_bounds__(256) void gemm3_mfma(
    const short* __restrict__ As_g, const short* __restrict__ Ws_g,
    const float* __restrict__ bias, float* __restrict__ C,
    short* __restrict__ Cs, int N, int KPi, int nchunk, int KPo)
{
    __shared__ short L[2][4][4096];
    const int tid = threadIdx.x;
    const int w = tid >> 6, lane = tid & 63;
    const int wr = w >> 1, wc = w & 1;
    const int m0 = blockIdx.y * 128, n0 = blockIdx.x * 128;
    const int frow = lane & 15, fk = (lane >> 4) * 8;
    const int srow = tid >> 2, scol = (tid & 3) * 8;
    const int RS = 2 * KPi;
    const int ld0 = w * 512;

    const short* gA0 = As_g + (size_t)(m0 + srow) * RS + scol;
    const short* gA1 = gA0 + (size_t)64 * RS;
    const short* gB0 = Ws_g + (size_t)(n0 + srow) * RS + scol;
    const short* gB1 = gB0 + (size_t)64 * RS;

    f32x4 acc[4][4] = {};

    auto stage = [&](int buf, int km) {
        GLL(gA0 + km,       &L[buf][0][ld0]);     GLL(gA1 + km,       &L[buf][0][ld0 + 2048]);
        GLL(gA0 + KPi + km, &L[buf][1][ld0]);     GLL(gA1 + KPi + km, &L[buf][1][ld0 + 2048]);
        GLL(gB0 + km,       &L[buf][2][ld0]);     GLL(gB1 + km,       &L[buf][2][ld0 + 2048]);
        GLL(gB0 + KPi + km, &L[buf][3][ld0]);     GLL(gB1 + KPi + km, &L[buf][3][ld0 + 2048]);
    };

    stage(0, 0);
    asm volatile("s_waitcnt vmcnt(0)" ::: "memory");
    __builtin_amdgcn_s_barrier();
    int buf = 0;
    #pragma unroll 1
    for (int cc = 0; cc < nchunk; ++cc) {
        if (cc + 1 < nchunk) {
            stage(buf ^ 1, (cc + 1) * 32);
            asm volatile("s_waitcnt vmcnt(8)" ::: "memory");
        } else {
            asm volatile("s_waitcnt vmcnt(0)" ::: "memory");
        }
        __builtin_amdgcn_s_barrier();

        bf16x8 ah[4], al[4], bh[4], bl[4];
        #pragma unroll
        for (int m = 0; m < 4; ++m) {
            const int ro = (wr * 64 + m * 16 + frow) * 32 + fk;
            ah[m] = *(const bf16x8*)&L[buf][0][ro];
            al[m] = *(const bf16x8*)&L[buf][1][ro];
        }
        #pragma unroll
        for (int n = 0; n < 4; ++n) {
            const int ro = (wc * 64 + n * 16 + frow) * 32 + fk;
            bh[n] = *(const bf16x8*)&L[buf][2][ro];
            bl[n] = *(const bf16x8*)&L[buf][3][ro];
        }
        #pragma unroll
        for (int m = 0; m < 4; ++m)
            #pragma unroll
            for (int n = 0; n < 4; ++n) {
                acc[m][n] = __builtin_amdgcn_mfma_f32_16x16x32_bf16(ah[m], bh[n], acc[m][n], 0, 0, 0);
                acc[m][n] = __builtin_amdgcn_mfma_f32_16x16x32_bf16(ah[m], bl[n], acc[m][n], 0, 0, 0);
                acc[m][n] = __builtin_amdgcn_mfma_f32_16x16x32_bf16(al[m], bh[n], acc[m][n], 0, 0, 0);
            }
        __builtin_amdgcn_s_barrier();
        buf ^= 1;
    }

    const int col0 = lane & 15;
    const int row4 = (lane >> 4) * 4;
    #pragma unroll
    for (int m = 0; m < 4; ++m) {
        #pragma unroll
        for (int r = 0; r < 4; ++r) {
            const int gm = m0 + wr * 64 + m * 16 + row4 + r;
            #pragma unroll
            for (int n = 0; n < 4; ++n) {
                const int gn = n0 + wc * 64 + n * 16 + col0;
                float v = 0.f;
                if (gn < N) {
                    v = acc[m][n][r] + bias[gn];
                    if (ACT == 1)      v = lrelu_f(v);
                    else if (ACT == 2) v = 1.f / (1.f + expf(-v));
                }
                if (WF32 && gn < N) C[(size_t)gm * N + gn] = v;
                if (WSPLIT && gn < KPo) {
                    short hi, lo; split1(v, hi, lo);
                    Cs[(size_t)gm * 2 * KPo + gn]       = hi;
                    Cs[(size_t)gm * 2 * KPo + KPo + gn] = lo;
                }
            }
        }
    }
}

// ---------------------------------------------------------------------------
// Fused: fc1 (3-term MFMA, blocks 0..127) + x-side light pdist (128x128
// hh-only, blocks 128..655). Both depend only on xs/sqx/w1s. 256 threads,
// 64 KiB LDS -> 2 blocks/CU; lights hide under the MLP chain.
// ---------------------------------------------------------------------------
__global__ __launch_bounds__(256) void fc1_xlight(
    const short* __restrict__ xs, const short* __restrict__ w1s,
    const float* __restrict__ fc1_b, short* __restrict__ h1s,
    const float* __restrict__ sqx, float* __restrict__ in_diff)
{
    __shared__ short L[2][4][4096];   // 64 KiB
    const int tid = threadIdx.x;
    const int w = tid >> 6, lane = tid & 63;
    const int wr = w >> 1, wc = w & 1;
    const int frow = lane & 15, fk = (lane >> 4) * 8;
    const int srow = tid >> 2, scol = (tid & 3) * 8;
    const int ld0 = w * 512;
    const int col0 = lane & 15;
    const int row4 = (lane >> 4) * 4;
    const int bid = blockIdx.x;

    if (bid < 128) {
        // ---------- fc1: xs[4096][1600] @ w1s[512][1600] -> h1s split ----------
        const int m0 = (bid >> 2) * 128, n0 = (bid & 3) * 128;
        const short* gA0 = xs  + (size_t)(m0 + srow) * 1600 + scol;
        const short* gA1 = gA0 + (size_t)64 * 1600;
        const short* gB0 = w1s + (size_t)(n0 + srow) * 1600 + scol;
        const short* gB1 = gB0 + (size_t)64 * 1600;

        f32x4 acc[4][4] = {};
        auto stage = [&](int buf, int km) {
            GLL(gA0 + km,       &L[buf][0][ld0]);   GLL(gA1 + km,       &L[buf][0][ld0 + 2048]);
            GLL(gA0 + 800 + km, &L[buf][1][ld0]);   GLL(gA1 + 800 + km, &L[buf][1][ld0 + 2048]);
            GLL(gB0 + km,       &L[buf][2][ld0]);   GLL(gB1 + km,       &L[buf][2][ld0 + 2048]);
            GLL(gB0 + 800 + km, &L[buf][3][ld0]);   GLL(gB1 + 800 + km, &L[buf][3][ld0 + 2048]);
        };
        stage(0, 0);
        asm volatile("s_waitcnt vmcnt(0)" ::: "memory");
        __builtin_amdgcn_s_barrier();
        int buf = 0;
        #pragma unroll 1
        for (int cc = 0; cc < 25; ++cc) {
            if (cc < 24) {
                stage(buf ^ 1, (cc + 1) * 32);
                asm volatile("s_waitcnt vmcnt(8)" ::: "memory");
            } else {
                asm volatile("s_waitcnt vmcnt(0)" ::: "memory");
            }
            __builtin_amdgcn_s_barrier();
            bf16x8 ah[4], al[4], bh[4], bl[4];
            #pragma unroll
            for (int m = 0; m < 4; ++m) {
                const int ro = (wr * 64 + m * 16 + frow) * 32 + fk;
                ah[m] = *(const bf16x8*)&L[buf][0][ro];
                al[m] = *(const bf16x8*)&L[buf][1][ro];
            }
            #pragma unroll
            for (int n = 0; n < 4; ++n) {
                const int ro = (wc * 64 + n * 16 + frow) * 32 + fk;
                bh[n] = *(const bf16x8*)&L[buf][2][ro];
                bl[n] = *(const bf16x8*)&L[buf][3][ro];
            }
            #pragma unroll
            for (int m = 0; m < 4; ++m)
                #pragma unroll
                for (int n = 0; n < 4; ++n) {
                    acc[m][n] = __builtin_amdgcn_mfma_f32_16x16x32_bf16(ah[m], bh[n], acc[m][n], 0, 0, 0);
                    acc[m][n] = __builtin_amdgcn_mfma_f32_16x16x32_bf16(ah[m], bl[n], acc[m][n], 0, 0, 0);
                    acc[m][n] = __builtin_amdgcn_mfma_f32_16x16x32_bf16(al[m], bh[n], acc[m][n], 0, 0, 0);
                }
            __builtin_amdgcn_s_barrier();
            buf ^= 1;
        }
        #pragma unroll
        for (int m = 0; m < 4; ++m) {
            #pragma unroll
            for (int r = 0; r < 4; ++r) {
                const int gm = m0 + wr * 64 + m * 16 + row4 + r;
                #pragma unroll
                for (int n = 0; n < 4; ++n) {
                    const int gn = n0 + wc * 64 + n * 16 + col0;
                    float v = 0.f;
                    if (gn < 400) v = lrelu_f(acc[m][n][r] + fc1_b[gn]);
                    if (gn < 416) {
                        short hi, lo; split1(v, hi, lo);
                        h1s[(size_t)gm * 832 + gn]       = hi;
                        h1s[(size_t)gm * 832 + 416 + gn] = lo;
                    }
                }
            }
        }
    } else {
        // ---------- light x-pdist: 128x128 tile, hh-only ----------
        const int o = bid - 128;
        const int b = (o & 7) * 66 + (o >> 3);    // bijective: 528 = 8*66
        int rem = b, ti = 0;
        while (rem >= 32 - ti) { rem -= 32 - ti; ++ti; }
        const int tj = ti + rem;
        const int i0 = ti * 128, j0 = tj * 128;

        const short* gA = xs + (size_t)(i0 + srow) * 1600 + scol;
        const short* gB = xs + (size_t)(j0 + srow) * 1600 + scol;

        f32x4 acc[4][4] = {};
        auto stageL = [&](int buf, int km) {
            GLL(gA + km,                    &L[buf][0][ld0]);
            GLL(gA + (size_t)64*1600 + km,  &L[buf][0][ld0 + 2048]);
            GLL(gB + km,                    &L[buf][1][ld0]);
            GLL(gB + (size_t)64*1600 + km,  &L[buf][1][ld0 + 2048]);
        };
        stageL(0, 0);
        asm volatile("s_waitcnt vmcnt(0)" ::: "memory");
        __builtin_amdgcn_s_barrier();
        int buf = 0;
        #pragma unroll 1
        for (int cc = 0; cc < 25; ++cc) {
            if (cc < 24) {
                stageL(buf ^ 1, (cc + 1) * 32);
                asm volatile("s_waitcnt vmcnt(4)" ::: "memory");
            } else {
                asm volatile("s_waitcnt vmcnt(0)" ::: "memory");
            }
            __builtin_amdgcn_s_barrier();
            bf16x8 a[4], bb[4];
            #pragma unroll
            for (int m = 0; m < 4; ++m)
                a[m] = *(const bf16x8*)&L[buf][0][(wr * 64 + m * 16 + frow) * 32 + fk];
            #pragma unroll
            for (int n = 0; n < 4; ++n)
                bb[n] = *(const bf16x8*)&L[buf][1][(wc * 64 + n * 16 + frow) * 32 + fk];
            #pragma unroll
            for (int m = 0; m < 4; ++m)
                #pragma unroll
                for (int n = 0; n < 4; ++n)
                    acc[m][n] = __builtin_amdgcn_mfma_f32_16x16x32_bf16(a[m], bb[n], acc[m][n], 0, 0, 0);
            __builtin_amdgcn_s_barrier();
            buf ^= 1;
        }
        float sqj_v[4];
        #pragma unroll
        for (int n = 0; n < 4; ++n)
            sqj_v[n] = sqx[j0 + wc * 64 + n * 16 + col0];
        #pragma unroll
        for (int m = 0; m < 4; ++m) {
            #pragma unroll
            for (int r = 0; r < 4; ++r) {
                const int gi = i0 + wr * 64 + m * 16 + row4 + r;
                const float sqi = sqx[gi];
                const int rowbase = (gi * (2 * NB - 1 - gi)) / 2 - gi - 1;
                #pragma unroll
                for (int n = 0; n < 4; ++n) {
                    const int gj = j0 + wc * 64 + n * 16 + col0;
                    if (gj > gi) {
                        float d2 = sqi + sqj_v[n] - 2.f * acc[m][n][r];
                        in_diff[rowbase + gj] = sqrtf(fmaxf(d2, 0.f));
                    }
                }
            }
        }
    }
}

// ---------------------------------------------------------------------------
// Fused mid-chain: h2 -> h3 = tanh(lrelu(fc12)) -> z = fc2 -> y1 = lrelu(fc3)
// -> y2 = lrelu(fc31) -> split y2s. 16 rows/block, 256 blocks.
// All operands staged in LDS coalesced; W12/W31 time-share one buffer.
// ---------------------------------------------------------------------------
__global__ __launch_bounds__(256) void fused_mid(
    const float* __restrict__ h2, const float* __restrict__ W12,
    const float* __restrict__ b12, const float* __restrict__ W2,
    const float* __restrict__ b2,  const float* __restrict__ W3,
    const float* __restrict__ b3,  const float* __restrict__ W31,
    const float* __restrict__ b31, float* __restrict__ z_out,
    short* __restrict__ y2s)
{
    __shared__ float wbuf[200 * 51];   // A: W12 as [50][201] (10050); B: W31 as [200][51]
    __shared__ float hl[16 * 201];
    __shared__ float h3l[16 * 51];
    __shared__ float y1l[16 * 51];
    __shared__ float zl[16 * 2];
    __shared__ float w2l[100], w3l[100];
    __shared__ float b12l[50], b2l[2], b3l[50], b31l[200];
    const int t = threadIdx.x;
    const int r0 = blockIdx.x * 16;

    for (int i = t; i < 50 * 200; i += 256) { int n = i / 200, k = i - n * 200; wbuf[n * 201 + k] = W12[i]; }
    for (int i = t; i < 16 * 200; i += 256) { int r = i / 200, k = i - r * 200; hl[r * 201 + k] = h2[(size_t)(r0 + r) * 200 + k]; }
    for (int i = t; i < 100; i += 256) { w2l[i] = W2[i]; w3l[i] = W3[i]; }
    if (t < 50)  { b12l[t] = b12[t]; b3l[t] = b3[t]; }
    if (t < 2)   b2l[t] = b2[t];
    if (t < 200) b31l[t] = b31[t];
    __syncthreads();

    // h3 = tanh(lrelu(h2 @ W12^T + b12))
    for (int i = t; i < 16 * 50; i += 256) {
        int r = i / 50, n = i - r * 50;
        float s = b12l[n];
        #pragma unroll 4
        for (int k = 0; k < 200; ++k) s = fmaf(hl[r * 201 + k], wbuf[n * 201 + k], s);
        h3l[r * 51 + n] = tanhf(lrelu_f(s));
    }
    __syncthreads();

    // z = h3 @ W2^T + b2 ; reload wbuf with W31
    if (t < 32) {
        int r = t >> 1, n = t & 1;
        float s = b2l[n];
        #pragma unroll
        for (int k = 0; k < 50; ++k) s = fmaf(h3l[r * 51 + k], w2l[n * 50 + k], s);
        zl[r * 2 + n] = s;
        z_out[(size_t)(r0 + r) * 2 + n] = s;
    }
    for (int i = t; i < 200 * 50; i += 256) { int n = i / 50, k = i - n * 50; wbuf[n * 51 + k] = W31[i]; }
    __syncthreads();

    // y1 = lrelu(z @ W3^T + b3)
    for (int i = t; i < 16 * 50; i += 256) {
        int r = i / 50, n = i - r * 50;
        float s = fmaf(zl[r * 2], w3l[n * 2], fmaf(zl[r * 2 + 1], w3l[n * 2 + 1], b3l[n]));
        y1l[r * 51 + n] = lrelu_f(s);
    }
    __syncthreads();

    // y2 = lrelu(y1 @ W31^T + b31) -> split into y2s [NB][2*224]
    for (int i = t; i < 16 * 224; i += 256) {
        int r = i / 224, n = i - r * 224;
        float v = 0.f;
        if (n < 200) {
            float s = b31l[n];
            #pragma unroll
            for (int k = 0; k < 50; ++k) s = fmaf(y1l[r * 51 + k], wbuf[n * 51 + k], s);
            v = lrelu_f(s);
        }
        short hi, lo; split1(v, hi, lo);
        const size_t gm = r0 + r;
        y2s[gm * 448 + n]       = hi;
        y2s[gm * 448 + 224 + n] = lo;
    }
}

// ---------------------------------------------------------------------------
// Final dispatch: blocks 0..135 heavy y-pdist (256x256, 3-term);
// blocks 136..663 z-pdist (128x128 direct-difference tiles) filling the
// CUs the heavies leave idle. 512 threads.
// ---------------------------------------------------------------------------
__global__ __launch_bounds__(512, 2) void pdist_heavy_z(
    const short* __restrict__ ys, const float* __restrict__ sqy,
    const float* __restrict__ Z, float* __restrict__ out_diff,
    float* __restrict__ lat_diff)
{
    __shared__ short L[2][4][8192];   // heavy: 128 KiB
    __shared__ float zi[128][2];
    __shared__ float zj[128][2];
    const int tid = threadIdx.x;
    const int w = tid >> 6, lane = tid & 63;
    const int frow = lane & 15, fk = (lane >> 4) * 8;
    const int col0 = lane & 15;
    const int row4 = (lane >> 4) * 4;
    const int orig = blockIdx.x;

    if (orig < 136) {
        // ---------------- heavy: y-side 256x256, 3-term ----------------
        const int b = (orig & 7) * 17 + (orig >> 3);
        int rem = b, ti = 0;
        while (rem >= 16 - ti) { rem -= 16 - ti; ++ti; }
        const int tj = ti + rem;

        const int wr = w >> 2, wc = w & 3;
        const int i0 = ti * 256, j0 = tj * 256;
        const int srow = w * 16 + (lane >> 2), scol = (lane & 3) * 8;
        const int ld0 = w * 512;

        const short* gA = ys + (size_t)(i0 + srow) * 1600 + scol;
        const short* gB = ys + (size_t)(j0 + srow) * 1600 + scol;
        const size_t half = (size_t)128 * 1600;

        f32x4 acc[8][4] = {};

        auto stage = [&](int buf, int km) {
            GLL(gA + km,       &L[buf][0][ld0]);   GLL(gA + half + km,       &L[buf][0][4096 + ld0]);
            GLL(gB + km,       &L[buf][2][ld0]);   GLL(gB + half + km,       &L[buf][2][4096 + ld0]);
            GLL(gA + 800 + km, &L[buf][1][ld0]);   GLL(gA + half + 800 + km, &L[buf][1][4096 + ld0]);
            GLL(gB + 800 + km, &L[buf][3][ld0]);   GLL(gB + half + 800 + km, &L[buf][3][4096 + ld0]);
        };

        stage(0, 0);
        asm volatile("s_waitcnt vmcnt(0)" ::: "memory");
        __builtin_amdgcn_s_barrier();
        int buf = 0;
        #pragma unroll 1
        for (int cc = 0; cc < 25; ++cc) {
            if (cc < 24) {
                stage(buf ^ 1, (cc + 1) * 32);
                asm volatile("s_waitcnt vmcnt(8)" ::: "memory");
            } else {
                asm volatile("s_waitcnt vmcnt(0)" ::: "memory");
            }
            __builtin_amdgcn_s_barrier();

            bf16x8 ah[8], bh[4];
            #pragma unroll
            for (int m = 0; m < 8; ++m)
                ah[m] = *(const bf16x8*)&L[buf][0][(wr * 128 + m * 16 + frow) * 32 + fk];
            #pragma unroll
            for (int n = 0; n < 4; ++n)
                bh[n] = *(const bf16x8*)&L[buf][2][(wc * 64 + n * 16 + frow) * 32 + fk];
            #pragma unroll
            for (int m = 0; m < 8; ++m)
                #pragma unroll
                for (int n = 0; n < 4; ++n)
                    acc[m][n] = __builtin_amdgcn_mfma_f32_16x16x32_bf16(ah[m], bh[n], acc[m][n], 0, 0, 0);
            {
                bf16x8 bl[4];
                #pragma unroll
                for (int n = 0; n < 4; ++n)
                    bl[n] = *(const bf16x8*)&L[buf][3][(wc * 64 + n * 16 + frow) * 32 + fk];
                #pragma unroll
                for (int m = 0; m < 8; ++m)
                    #pragma unroll
                    for (int n = 0; n < 4; ++n)
                        acc[m][n] = __builtin_amdgcn_mfma_f32_16x16x32_bf16(ah[m], bl[n], acc[m][n], 0, 0, 0);
            }
            {
                bf16x8 al[8];
                #pragma unroll
                for (int m = 0; m < 8; ++m)
                    al[m] = *(const bf16x8*)&L[buf][1][(wr * 128 + m * 16 + frow) * 32 + fk];
                #pragma unroll
                for (int m = 0; m < 8; ++m)
                    #pragma unroll
                    for (int n = 0; n < 4; ++n)
                        acc[m][n] = __builtin_amdgcn_mfma_f32_16x16x32_bf16(al[m], bh[n], acc[m][n], 0, 0, 0);
            }
            __builtin_amdgcn_s_barrier();
            buf ^= 1;
        }

        float sqj_v[4];
        #pragma unroll
        for (int n = 0; n < 4; ++n)
            sqj_v[n] = sqy[j0 + wc * 64 + n * 16 + col0];

        #pragma unroll
        for (int m = 0; m < 8; ++m) {
            #pragma unroll
            for (int r = 0; r < 4; ++r) {
                const int gi = i0 + wr * 128 + m * 16 + row4 + r;
                const float sqi = sqy[gi];
                const int rowbase = (gi * (2 * NB - 1 - gi)) / 2 - gi - 1;
                #pragma unroll
                for (int n = 0; n < 4; ++n) {
                    const int gj = j0 + wc * 64 + n * 16 + col0;
                    if (gj > gi) {
                        float d2 = sqi + sqj_v[n] - 2.f * acc[m][n][r];
                        out_diff[rowbase + gj] = sqrtf(fmaxf(d2, 0.f));
                    }
                }
            }
        }
    } else {
        // ---------------- z-pdist: 128x128 direct-difference tile ----------------
        const int o = orig - 136;
        const int b = (o & 7) * 66 + (o >> 3);    // 528 = 8*66
        int rem = b, ti = 0;
        while (rem >= 32 - ti) { rem -= 32 - ti; ++ti; }
        const int tj = ti + rem;
        const int i0 = ti * 128, j0 = tj * 128;

        if (tid < 256) {
            int r = tid >> 1, c = tid & 1;
            zi[r][c] = Z[(size_t)(i0 + r) * 2 + c];
        } else {
            int q = tid - 256;
            int r = q >> 1, c = q & 1;
            zj[r][c] = Z[(size_t)(j0 + r) * 2 + c];
        }
        __syncthreads();

        const int ty = tid >> 5;   // 0..15 -> 8 i-rows each
        const int tx = tid & 31;   // 0..31 -> 4 j-cols each
        #pragma unroll
        for (int ii = 0; ii < 8; ++ii) {
            const int li = ty * 8 + ii;
            const int gi = i0 + li;
            const int rowbase = (gi * (2 * NB - 1 - gi)) / 2 - gi - 1;
            const float zi0 = zi[li][0], zi1 = zi[li][1];
            #pragma unroll
            for (int jj = 0; jj < 4; ++jj) {
                const int lj = tx * 4 + jj;
                const int gj = j0 + lj;
                if (gj > gi) {
                    float d0 = zi0 - zj[lj][0];
                    float d1 = zi1 - zj[lj][1];
                    lat_diff[rowbase + gj] = sqrtf(fmaf(d0, d0, d1 * d1));
                }
            }
        }
    }
}

// ---------------------------------------------------------------------------
extern "C" void kernel_launch(void* const* d_in, const int* in_sizes, int n_in,
                              void* d_out, int out_size, void* d_ws, size_t ws_size,
                              hipStream_t stream)
{
    const float* x       = (const float*)d_in[0];
    const float* fc1_w   = (const float*)d_in[1];
    const float* fc1_b   = (const float*)d_in[2];
    const float* fc11_w  = (const float*)d_in[3];
    const float* fc11_b  = (const float*)d_in[4];
    const float* fc12_w  = (const float*)d_in[5];
    const float* fc12_b  = (const float*)d_in[6];
    const float* fc2_w   = (const float*)d_in[7];
    const float* fc2_b   = (const float*)d_in[8];
    const float* fc3_w   = (const float*)d_in[9];
    const float* fc3_b   = (const float*)d_in[10];
    const float* fc31_w  = (const float*)d_in[11];
    const float* fc31_b  = (const float*)d_in[12];
    const float* fc32_w  = (const float*)d_in[13];
    const float* fc32_b  = (const float*)d_in[14];
    const float* fc4_w   = (const float*)d_in[15];
    const float* fc4_b   = (const float*)d_in[16];

    float* out = (float*)d_out;
    float* y        = out;                 // 4096*784
    float* in_diff  = out + 3211264;       // 8386560
    float* lat_diff = out + 11597824;      // 8386560
    float* out_diff = out + 19984384;      // 8386560
    float* z        = out + 28370944;      // 4096*2

    // ---- workspace layout (r9-proven) ----
    float* ws   = (float*)d_ws;
    float* h2   = ws;                          // 4096*200 f32
    float* h3u  = h2  + (size_t)4096 * 200;    // unused slots kept for layout
    float* y1u  = h3u + (size_t)4096 * 50;
    float* sqx  = y1u + (size_t)4096 * 50;     // 4096
    float* sqy  = sqx + 4096;                  // 4096
    short* xs   = (short*)(sqy + 4096);        // 4096*1600
    short* ys   = xs  + (size_t)NB * 1600;     // 4096*1600
    short* w1s  = ys  + (size_t)NB * 1600;     // 512*1600
    short* w11s = w1s  + (size_t)512 * 1600;   // 256*832
    short* w32s = w11s + (size_t)256 * 832;    // 512*448
    short* w4s  = w32s + (size_t)512 * 448;    // 896*832
    short* h1s  = w4s  + (size_t)896 * 832;    // 4096*832
    short* y3s  = h1s;                         // alias: h1s dead after fc11
    short* y2s  = h1s  + (size_t)4096 * 832;   // 4096*448

    const dim3 blk(256);

    // 1. all weight splits
    split_w_all<<<dim3(3920), blk, 0, stream>>>(
        fc1_w, fc11_w, fc32_w, fc4_w, w1s, w11s, w32s, w4s);
    // 2. x prep
    split_x_rowsq<<<dim3(NB), blk, 0, stream>>>(x, xs, sqx);
    // 3. fc1 + x-light pdist (independent work, one dispatch)
    fc1_xlight<<<dim3(656), blk, 0, stream>>>(xs, w1s, fc1_b, h1s, sqx, in_diff);
    // 4. fc1_1
    gemm3_mfma<1, true, false><<<dim3(2, 32), blk, 0, stream>>>(
        h1s, w11s, fc11_b, h2, nullptr, 200, 416, 13, 0);
    // 5. fused mid-chain: h2 -> h3 -> z -> y1 -> y2s
    fused_mid<<<dim3(256), blk, 0, stream>>>(
        h2, fc12_w, fc12_b, fc2_w, fc2_b, fc3_w, fc3_b, fc31_w, fc31_b, z, y2s);
    // 6. fc3_2
    gemm3_mfma<1, false, true><<<dim3(4, 32), blk, 0, stream>>>(
        y2s, w32s, fc32_b, nullptr, y3s, 400, 224, 7, 416);
    // 7. fc4 -> y + ys
    gemm3_mfma<2, true, true><<<dim3(7, 32), blk, 0, stream>>>(
        y3s, w4s, fc4_b, y, ys, 784, 416, 13, 800);
    // 8. y norms
    rowsq_kernel<<<dim3(NB), blk, 0, stream>>>(y, sqy, DIMX);
    // 9. heavy y-pdist + z-pdist
    pdist_heavy_z<<<dim3(664), dim3(512), 0, stream>>>(ys, sqy, z, out_diff, lat_diff);
}

// Round 11
// 266.114 us; speedup vs baseline: 1.5976x; 1.0384x over previous
//
#include <hip/hip_runtime.h>
#include <math.h>

#define NB 4096            // batch
#define DIMX 784           // feature dim for x / y pdists

typedef __attribute__((ext_vector_type(8))) short bf16x8;
typedef __attribute__((ext_vector_type(4))) float f32x4;

__device__ __forceinline__ float lrelu_f(float v) { return v >= 0.f ? v : 0.01f * v; }

// round-to-nearest-even fp32 -> bf16 hi, residual -> bf16 lo
__device__ __forceinline__ void split1(float x, short& hi_s, short& lo_s) {
    unsigned u = __float_as_uint(x);
    unsigned hib = (u + 0x7FFFu + ((u >> 16) & 1u)) & 0xFFFF0000u;
    float hif = __uint_as_float(hib);
    float lo = x - hif;
    unsigned ul = __float_as_uint(lo);
    unsigned lob = (ul + 0x7FFFu + ((ul >> 16) & 1u)) >> 16;
    hi_s = (short)(hib >> 16);
    lo_s = (short)lob;
}

#define GLL(srcp, dstp) __builtin_amdgcn_global_load_lds( \
    (const __attribute__((address_space(1))) void*)(srcp), \
    (__attribute__((address_space(3))) void*)(dstp), 16, 0, 0)

// Swizzle (T2, both-sides involution keyed on (row>>1)&3):
//   stage source col-block: (tid&3) ^ ((tid>>3)&3)        [srow = tid>>2]
//   read k-slot:            (lane>>4) ^ ((lane>>1)&3)     [frow = lane&15]
// LDS stays linear (global_load_lds requirement); global col-blocks permuted.

// ---------------------------------------------------------------------------
// All four weight splits in ONE dispatch (block-range switch).
// ---------------------------------------------------------------------------
__global__ __launch_bounds__(256) void split_w_all(
    const float* __restrict__ w1, const float* __restrict__ w11,
    const float* __restrict__ w32, const float* __restrict__ w4,
    short* __restrict__ o1, short* __restrict__ o11,
    short* __restrict__ o32, short* __restrict__ o4)
{
    const int bid = blockIdx.x;
    const float* W; short* O; int N, K, NP, KP, base;
    if (bid < 1600)      { W = w1;  O = o1;  N = 400; K = 784; NP = 512; KP = 800; base = 0; }
    else if (bid < 2016) { W = w11; O = o11; N = 200; K = 400; NP = 256; KP = 416; base = 1600; }
    else if (bid < 2464) { W = w32; O = o32; N = 400; K = 200; NP = 512; KP = 224; base = 2016; }
    else                 { W = w4;  O = o4;  N = 784; K = 400; NP = 896; KP = 416; base = 2464; }
    const int idx = (bid - base) * 256 + threadIdx.x;
    if (idx >= NP * KP) return;
    const int r = idx / KP, k = idx - r * KP;
    short hi = 0, lo = 0;
    if (r < N && k < K) split1(W[(size_t)r * K + k], hi, lo);
    O[(size_t)r * 2 * KP + k]      = hi;
    O[(size_t)r * 2 * KP + KP + k] = lo;
}

// ---------------------------------------------------------------------------
// Fused x prep: one block per row. split [hi(800)|lo(800)] + row sq-norm.
// ---------------------------------------------------------------------------
__global__ __launch_bounds__(256) void split_x_rowsq(
    const float* __restrict__ X, short* __restrict__ Xs, float* __restrict__ sq)
{
    const int r = blockIdx.x, t = threadIdx.x;
    float s = 0.f;
    if (t < 200) {
        const int k0 = t * 4;
        short h[4] = {0, 0, 0, 0}, l[4] = {0, 0, 0, 0};
        if (k0 < 784) {
            float4 v = *(const float4*)(X + (size_t)r * 784 + k0);
            split1(v.x, h[0], l[0]); split1(v.y, h[1], l[1]);
            split1(v.z, h[2], l[2]); split1(v.w, h[3], l[3]);
            s = v.x * v.x + v.y * v.y + v.z * v.z + v.w * v.w;
        }
        *(uint2*)&Xs[(size_t)r * 1600 + k0]       = *(const uint2*)h;
        *(uint2*)&Xs[(size_t)r * 1600 + 800 + k0] = *(const uint2*)l;
    }
    __shared__ float red[256];
    red[t] = s;
    __syncthreads();
    for (int off = 128; off > 0; off >>= 1) {
        if (t < off) red[t] += red[t + off];
        __syncthreads();
    }
    if (t == 0) sq[r] = red[0];
}

// ---------------------------------------------------------------------------
// Row squared-norms (fp32 exact) — y
// ---------------------------------------------------------------------------
__global__ __launch_bounds__(256) void rowsq_kernel(
    const float* __restrict__ X, float* __restrict__ sq, int K)
{
    const int r = blockIdx.x;
    const int tid = threadIdx.x;
    float s = 0.f;
    const float* row = X + (size_t)r * K;
    for (int k = tid; k < K; k += 256) { float v = row[k]; s = fmaf(v, v, s); }
    __shared__ float red[256];
    red[tid] = s;
    __syncthreads();
    for (int off = 128; off > 0; off >>= 1) {
        if (tid < off) red[tid] += red[tid + off];
        __syncthreads();
    }
    if (tid == 0) sq[r] = red[0];
}

// ---------------------------------------------------------------------------
// bf16-split MFMA GEMM, 3-TERM (hh + hl + lh). 128x128 tile, BK=32, 4 waves,
// counted-vmcnt double-buffer pipeline + T2 swizzle.
// ---------------------------------------------------------------------------
template<int ACT, bool WF32, bool WSPLIT>
__global__ __launch_bounds__(256) void gemm3_mfma(
    const short* __restrict__ As_g, const short* __restrict__ Ws_g,
    const float* __restrict__ bias, float* __restrict__ C,
    short* __restrict__ Cs, int N, int KPi, int nchunk, int KPo)
{
    __shared__ short L[2][4][4096];
    const int tid = threadIdx.x;
    const int w = tid >> 6, lane = tid & 63;
    const int wr = w >> 1, wc = w & 1;
    const int m0 = blockIdx.y * 128, n0 = blockIdx.x * 128;
    const int frow = lane & 15;
    const int fk_sw = (((lane >> 4) ^ ((lane >> 1) & 3))) * 8;
    const int srow = tid >> 2;
    const int scol_sw = (((tid & 3) ^ ((tid >> 3) & 3))) * 8;
    const int RS = 2 * KPi;
    const int ld0 = w * 512;

    const short* gA0 = As_g + (size_t)(m0 + srow) * RS + scol_sw;
    const short* gA1 = gA0 + (size_t)64 * RS;
    const short* gB0 = Ws_g + (size_t)(n0 + srow) * RS + scol_sw;
    const short* gB1 = gB0 + (size_t)64 * RS;

    f32x4 acc[4][4] = {};

    auto stage = [&](int buf, int km) {
        GLL(gA0 + km,       &L[buf][0][ld0]);     GLL(gA1 + km,       &L[buf][0][ld0 + 2048]);
        GLL(gA0 + KPi + km, &L[buf][1][ld0]);     GLL(gA1 + KPi + km, &L[buf][1][ld0 + 2048]);
        GLL(gB0 + km,       &L[buf][2][ld0]);     GLL(gB1 + km,       &L[buf][2][ld0 + 2048]);
        GLL(gB0 + KPi + km, &L[buf][3][ld0]);     GLL(gB1 + KPi + km, &L[buf][3][ld0 + 2048]);
    };

    stage(0, 0);
    asm volatile("s_waitcnt vmcnt(0)" ::: "memory");
    __builtin_amdgcn_s_barrier();
    int buf = 0;
    #pragma unroll 1
    for (int cc = 0; cc < nchunk; ++cc) {
        if (cc + 1 < nchunk) {
            stage(buf ^ 1, (cc + 1) * 32);
            asm volatile("s_waitcnt vmcnt(8)" ::: "memory");
        } else {
            asm volatile("s_waitcnt vmcnt(0)" ::: "memory");
        }
        __builtin_amdgcn_s_barrier();

        bf16x8 ah[4], al[4], bh[4], bl[4];
        #pragma unroll
        for (int m = 0; m < 4; ++m) {
            const int ro = (wr * 64 + m * 16 + frow) * 32 + fk_sw;
            ah[m] = *(const bf16x8*)&L[buf][0][ro];
            al[m] = *(const bf16x8*)&L[buf][1][ro];
        }
        #pragma unroll
        for (int n = 0; n < 4; ++n) {
            const int ro = (wc * 64 + n * 16 + frow) * 32 + fk_sw;
            bh[n] = *(const bf16x8*)&L[buf][2][ro];
            bl[n] = *(const bf16x8*)&L[buf][3][ro];
        }
        #pragma unroll
        for (int m = 0; m < 4; ++m)
            #pragma unroll
            for (int n = 0; n < 4; ++n) {
                acc[m][n] = __builtin_amdgcn_mfma_f32_16x16x32_bf16(ah[m], bh[n], acc[m][n], 0, 0, 0);
                acc[m][n] = __builtin_amdgcn_mfma_f32_16x16x32_bf16(ah[m], bl[n], acc[m][n], 0, 0, 0);
                acc[m][n] = __builtin_amdgcn_mfma_f32_16x16x32_bf16(al[m], bh[n], acc[m][n], 0, 0, 0);
            }
        __builtin_amdgcn_s_barrier();
        buf ^= 1;
    }

    const int col0 = lane & 15;
    const int row4 = (lane >> 4) * 4;
    #pragma unroll
    for (int m = 0; m < 4; ++m) {
        #pragma unroll
        for (int r = 0; r < 4; ++r) {
            const int gm = m0 + wr * 64 + m * 16 + row4 + r;
            #pragma unroll
            for (int n = 0; n < 4; ++n) {
                const int gn = n0 + wc * 64 + n * 16 + col0;
                float v = 0.f;
                if (gn < N) {
                    v = acc[m][n][r] + bias[gn];
                    if (ACT == 1)      v = lrelu_f(v);
                    else if (ACT == 2) v = 1.f / (1.f + expf(-v));
                }
                if (WF32 && gn < N) C[(size_t)gm * N + gn] = v;
                if (WSPLIT && gn < KPo) {
                    short hi, lo; split1(v, hi, lo);
                    Cs[(size_t)gm * 2 * KPo + gn]       = hi;
                    Cs[(size_t)gm * 2 * KPo + KPo + gn] = lo;
                }
            }
        }
    }
}

// ---------------------------------------------------------------------------
// Fused mid-chain: h2 -> h3 -> z -> y1 -> y2s (r10-proven)
// ---------------------------------------------------------------------------
__global__ __launch_bounds__(256) void fused_mid(
    const float* __restrict__ h2, const float* __restrict__ W12,
    const float* __restrict__ b12, const float* __restrict__ W2,
    const float* __restrict__ b2,  const float* __restrict__ W3,
    const float* __restrict__ b3,  const float* __restrict__ W31,
    const float* __restrict__ b31, float* __restrict__ z_out,
    short* __restrict__ y2s)
{
    __shared__ float wbuf[200 * 51];
    __shared__ float hl[16 * 201];
    __shared__ float h3l[16 * 51];
    __shared__ float y1l[16 * 51];
    __shared__ float zl[16 * 2];
    __shared__ float w2l[100], w3l[100];
    __shared__ float b12l[50], b2l[2], b3l[50], b31l[200];
    const int t = threadIdx.x;
    const int r0 = blockIdx.x * 16;

    for (int i = t; i < 50 * 200; i += 256) { int n = i / 200, k = i - n * 200; wbuf[n * 201 + k] = W12[i]; }
    for (int i = t; i < 16 * 200; i += 256) { int r = i / 200, k = i - r * 200; hl[r * 201 + k] = h2[(size_t)(r0 + r) * 200 + k]; }
    for (int i = t; i < 100; i += 256) { w2l[i] = W2[i]; w3l[i] = W3[i]; }
    if (t < 50)  { b12l[t] = b12[t]; b3l[t] = b3[t]; }
    if (t < 2)   b2l[t] = b2[t];
    if (t < 200) b31l[t] = b31[t];
    __syncthreads();

    for (int i = t; i < 16 * 50; i += 256) {
        int r = i / 50, n = i - r * 50;
        float s = b12l[n];
        #pragma unroll 4
        for (int k = 0; k < 200; ++k) s = fmaf(hl[r * 201 + k], wbuf[n * 201 + k], s);
        h3l[r * 51 + n] = tanhf(lrelu_f(s));
    }
    __syncthreads();

    if (t < 32) {
        int r = t >> 1, n = t & 1;
        float s = b2l[n];
        #pragma unroll
        for (int k = 0; k < 50; ++k) s = fmaf(h3l[r * 51 + k], w2l[n * 50 + k], s);
        zl[r * 2 + n] = s;
        z_out[(size_t)(r0 + r) * 2 + n] = s;
    }
    for (int i = t; i < 200 * 50; i += 256) { int n = i / 50, k = i - n * 50; wbuf[n * 51 + k] = W31[i]; }
    __syncthreads();

    for (int i = t; i < 16 * 50; i += 256) {
        int r = i / 50, n = i - r * 50;
        float s = fmaf(zl[r * 2], w3l[n * 2], fmaf(zl[r * 2 + 1], w3l[n * 2 + 1], b3l[n]));
        y1l[r * 51 + n] = lrelu_f(s);
    }
    __syncthreads();

    for (int i = t; i < 16 * 224; i += 256) {
        int r = i / 224, n = i - r * 224;
        float v = 0.f;
        if (n < 200) {
            float s = b31l[n];
            #pragma unroll
            for (int k = 0; k < 50; ++k) s = fmaf(y1l[r * 51 + k], wbuf[n * 51 + k], s);
            v = lrelu_f(s);
        }
        short hi, lo; split1(v, hi, lo);
        const size_t gm = r0 + r;
        y2s[gm * 448 + n]       = hi;
        y2s[gm * 448 + 224 + n] = lo;
    }
}

// ---------------------------------------------------------------------------
// Mega pdist: 1584 blocks x 256 thr, m97-style single-buffer 32 KiB LDS
// -> 4 blocks/CU (16 waves/CU) for wave-level latency overlap.
//   blocks 0..527    : y-side 128x128, 3-term (hh+hl+lh)
//   blocks 528..1055 : x-side 128x128, hh-only
//   blocks 1056..1583: z-side 128x128 direct-difference
// T2 swizzle on stage-source + reads. Per-set XCD swizzle (528 = 8*66).
// ---------------------------------------------------------------------------
__global__ __launch_bounds__(256, 4) void pdist_tri(
    const short* __restrict__ xs, const short* __restrict__ ys,
    const float* __restrict__ sqx, const float* __restrict__ sqy,
    const float* __restrict__ Z, float* __restrict__ in_diff,
    float* __restrict__ out_diff, float* __restrict__ lat_diff)
{
    __shared__ short L[4][4096];   // 32 KiB: Ah, Al, Bh, Bl
    const int tid = threadIdx.x;
    const int orig = blockIdx.x;

    if (orig < 1056) {
        const bool heavy = (orig < 528);
        const int o = heavy ? orig : orig - 528;
        const int b = (o & 7) * 66 + (o >> 3);     // bijective: 528 = 8*66
        int rem = b, ti = 0;
        while (rem >= 32 - ti) { rem -= 32 - ti; ++ti; }
        const int tj = ti + rem;

        const short* Xs = heavy ? ys : xs;
        const float* sq = heavy ? sqy : sqx;
        float* outp     = heavy ? out_diff : in_diff;

        const int w = tid >> 6, lane = tid & 63;
        const int wr = w >> 1, wc = w & 1;
        const int frow = lane & 15;
        const int fk_sw = (((lane >> 4) ^ ((lane >> 1) & 3))) * 8;
        const int srow = tid >> 2;
        const int scol_sw = (((tid & 3) ^ ((tid >> 3) & 3))) * 8;
        const int i0 = ti * 128, j0 = tj * 128;
        const int ld0 = w * 512;

        const short* gA = Xs + (size_t)(i0 + srow) * 1600 + scol_sw;
        const short* gB = Xs + (size_t)(j0 + srow) * 1600 + scol_sw;
        const size_t half = (size_t)64 * 1600;

        f32x4 acc[4][4] = {};

        #pragma unroll 1
        for (int cc = 0; cc < 25; ++cc) {
            const int km = cc * 32;
            __syncthreads();                 // prev reads done -> safe to overwrite
            GLL(gA + km,        &L[0][ld0]);   GLL(gA + half + km,        &L[0][2048 + ld0]);
            GLL(gB + km,        &L[2][ld0]);   GLL(gB + half + km,        &L[2][2048 + ld0]);
            if (heavy) {
                GLL(gA + 800 + km, &L[1][ld0]);   GLL(gA + half + 800 + km, &L[1][2048 + ld0]);
                GLL(gB + 800 + km, &L[3][ld0]);   GLL(gB + half + 800 + km, &L[3][2048 + ld0]);
            }
            __syncthreads();                 // compiler drains vmcnt before barrier

            bf16x8 ah[4], bh[4];
            #pragma unroll
            for (int m = 0; m < 4; ++m)
                ah[m] = *(const bf16x8*)&L[0][(wr * 64 + m * 16 + frow) * 32 + fk_sw];
            #pragma unroll
            for (int n = 0; n < 4; ++n)
                bh[n] = *(const bf16x8*)&L[2][(wc * 64 + n * 16 + frow) * 32 + fk_sw];
            #pragma unroll
            for (int m = 0; m < 4; ++m)
                #pragma unroll
                for (int n = 0; n < 4; ++n)
                    acc[m][n] = __builtin_amdgcn_mfma_f32_16x16x32_bf16(ah[m], bh[n], acc[m][n], 0, 0, 0);

            if (heavy) {
                bf16x8 al[4], bl[4];
                #pragma unroll
                for (int n = 0; n < 4; ++n)
                    bl[n] = *(const bf16x8*)&L[3][(wc * 64 + n * 16 + frow) * 32 + fk_sw];
                #pragma unroll
                for (int m = 0; m < 4; ++m)
                    #pragma unroll
                    for (int n = 0; n < 4; ++n)
                        acc[m][n] = __builtin_amdgcn_mfma_f32_16x16x32_bf16(ah[m], bl[n], acc[m][n], 0, 0, 0);
                #pragma unroll
                for (int m = 0; m < 4; ++m)
                    al[m] = *(const bf16x8*)&L[1][(wr * 64 + m * 16 + frow) * 32 + fk_sw];
                #pragma unroll
                for (int m = 0; m < 4; ++m)
                    #pragma unroll
                    for (int n = 0; n < 4; ++n)
                        acc[m][n] = __builtin_amdgcn_mfma_f32_16x16x32_bf16(al[m], bh[n], acc[m][n], 0, 0, 0);
            }
        }

        const int col0 = lane & 15;
        const int row4 = (lane >> 4) * 4;
        float sqj_v[4];
        #pragma unroll
        for (int n = 0; n < 4; ++n)
            sqj_v[n] = sq[j0 + wc * 64 + n * 16 + col0];

        #pragma unroll
        for (int m = 0; m < 4; ++m) {
            #pragma unroll
            for (int r = 0; r < 4; ++r) {
                const int gi = i0 + wr * 64 + m * 16 + row4 + r;
                const float sqi = sq[gi];
                const int rowbase = (gi * (2 * NB - 1 - gi)) / 2 - gi - 1;
                #pragma unroll
                for (int n = 0; n < 4; ++n) {
                    const int gj = j0 + wc * 64 + n * 16 + col0;
                    if (gj > gi) {
                        float d2 = sqi + sqj_v[n] - 2.f * acc[m][n][r];
                        outp[rowbase + gj] = sqrtf(fmaxf(d2, 0.f));
                    }
                }
            }
        }
    } else {
        // ---------------- z-pdist: 128x128 direct-difference tile ----------------
        const int o = orig - 1056;
        const int b = (o & 7) * 66 + (o >> 3);
        int rem = b, ti = 0;
        while (rem >= 32 - ti) { rem -= 32 - ti; ++ti; }
        const int tj = ti + rem;
        const int i0 = ti * 128, j0 = tj * 128;

        float* zi = (float*)&L[0][0];        // 128*2 floats
        float* zj = (float*)&L[0][512];      // 128*2 floats
        if (tid < 128) {
            *(float2*)&zi[tid * 2] = *(const float2*)&Z[(size_t)(i0 + tid) * 2];
        } else {
            const int r = tid - 128;
            *(float2*)&zj[r * 2] = *(const float2*)&Z[(size_t)(j0 + r) * 2];
        }
        __syncthreads();

        const int ty = tid >> 4;   // 0..15 -> 8 rows each
        const int tx = tid & 15;   // 0..15 -> 8 cols each
        #pragma unroll
        for (int ii = 0; ii < 8; ++ii) {
            const int li = ty * 8 + ii;
            const int gi = i0 + li;
            const int rowbase = (gi * (2 * NB - 1 - gi)) / 2 - gi - 1;
            const float zi0 = zi[li * 2], zi1 = zi[li * 2 + 1];
            #pragma unroll
            for (int jj = 0; jj < 8; ++jj) {
                const int lj = tx * 8 + jj;
                const int gj = j0 + lj;
                if (gj > gi) {
                    float d0 = zi0 - zj[lj * 2];
                    float d1 = zi1 - zj[lj * 2 + 1];
                    lat_diff[rowbase + gj] = sqrtf(fmaf(d0, d0, d1 * d1));
                }
            }
        }
    }
}

// ---------------------------------------------------------------------------
extern "C" void kernel_launch(void* const* d_in, const int* in_sizes, int n_in,
                              void* d_out, int out_size, void* d_ws, size_t ws_size,
                              hipStream_t stream)
{
    const float* x       = (const float*)d_in[0];
    const float* fc1_w   = (const float*)d_in[1];
    const float* fc1_b   = (const float*)d_in[2];
    const float* fc11_w  = (const float*)d_in[3];
    const float* fc11_b  = (const float*)d_in[4];
    const float* fc12_w  = (const float*)d_in[5];
    const float* fc12_b  = (const float*)d_in[6];
    const float* fc2_w   = (const float*)d_in[7];
    const float* fc2_b   = (const float*)d_in[8];
    const float* fc3_w   = (const float*)d_in[9];
    const float* fc3_b   = (const float*)d_in[10];
    const float* fc31_w  = (const float*)d_in[11];
    const float* fc31_b  = (const float*)d_in[12];
    const float* fc32_w  = (const float*)d_in[13];
    const float* fc32_b  = (const float*)d_in[14];
    const float* fc4_w   = (const float*)d_in[15];
    const float* fc4_b   = (const float*)d_in[16];

    float* out = (float*)d_out;
    float* y        = out;                 // 4096*784
    float* in_diff  = out + 3211264;       // 8386560
    float* lat_diff = out + 11597824;      // 8386560
    float* out_diff = out + 19984384;      // 8386560
    float* z        = out + 28370944;      // 4096*2

    // ---- workspace layout (r9/r10-proven) ----
    float* ws   = (float*)d_ws;
    float* h2   = ws;                          // 4096*200 f32
    float* h3u  = h2  + (size_t)4096 * 200;
    float* y1u  = h3u + (size_t)4096 * 50;
    float* sqx  = y1u + (size_t)4096 * 50;     // 4096
    float* sqy  = sqx + 4096;                  // 4096
    short* xs   = (short*)(sqy + 4096);        // 4096*1600
    short* ys   = xs  + (size_t)NB * 1600;     // 4096*1600
    short* w1s  = ys  + (size_t)NB * 1600;     // 512*1600
    short* w11s = w1s  + (size_t)512 * 1600;   // 256*832
    short* w32s = w11s + (size_t)256 * 832;    // 512*448
    short* w4s  = w32s + (size_t)512 * 448;    // 896*832
    short* h1s  = w4s  + (size_t)896 * 832;    // 4096*832
    short* y3s  = h1s;                         // alias: h1s dead after fc11
    short* y2s  = h1s  + (size_t)4096 * 832;   // 4096*448

    const dim3 blk(256);

    // 1. all weight splits
    split_w_all<<<dim3(3920), blk, 0, stream>>>(
        fc1_w, fc11_w, fc32_w, fc4_w, w1s, w11s, w32s, w4s);
    // 2. x prep
    split_x_rowsq<<<dim3(NB), blk, 0, stream>>>(x, xs, sqx);
    // 3. fc1
    gemm3_mfma<1, false, true><<<dim3(4, 32), blk, 0, stream>>>(
        xs, w1s, fc1_b, nullptr, h1s, 400, 800, 25, 416);
    // 4. fc1_1
    gemm3_mfma<1, true, false><<<dim3(2, 32), blk, 0, stream>>>(
        h1s, w11s, fc11_b, h2, nullptr, 200, 416, 13, 0);
    // 5. fused mid-chain: h2 -> h3 -> z -> y1 -> y2s
    fused_mid<<<dim3(256), blk, 0, stream>>>(
        h2, fc12_w, fc12_b, fc2_w, fc2_b, fc3_w, fc3_b, fc31_w, fc31_b, z, y2s);
    // 6. fc3_2
    gemm3_mfma<1, false, true><<<dim3(4, 32), blk, 0, stream>>>(
        y2s, w32s, fc32_b, nullptr, y3s, 400, 224, 7, 416);
    // 7. fc4 -> y + ys
    gemm3_mfma<2, true, true><<<dim3(7, 32), blk, 0, stream>>>(
        y3s, w4s, fc4_b, y, ys, 784, 416, 13, 800);
    // 8. y norms
    rowsq_kernel<<<dim3(NB), blk, 0, stream>>>(y, sqy, DIMX);
    // 9. mega pdist: y-heavy + x-light + z
    pdist_tri<<<dim3(1584), blk, 0, stream>>>(
        xs, ys, sqx, sqy, z, in_diff, out_diff, lat_diff);
}